// Round 5
// baseline (1942.265 us; speedup 1.0000x reference)
//
#include <hip/hip_runtime.h>
#include <math.h>

#define N_NODES 200000
#define N_EDGES 5000000
#define NFEAT 16
#define DIM 10
#define DIMP 11          // LDS agg row stride (gcd(11,32)=1 breaks bank pattern)
#define NGRAPH 1000
#define BSH 8            // 256 nodes per dst bucket
#define BNODES 256
#define NB ((N_NODES + BNODES - 1) / BNODES)   // 782
#define GSH 12           // src group = src>>12 (4096-node, 80KB window)
#define NGRP ((N_NODES >> GSH) + 1)            // 49
#define CBLK 320
#define LTB 512          // gin_layer block size

// pack two f32 -> two bf16 (RNE) in one u32
__device__ __forceinline__ unsigned pkbf(float a, float b) {
    unsigned ua = __float_as_uint(a), ub = __float_as_uint(b);
    ua = (ua + 0x7fffu + ((ua >> 16) & 1u)) >> 16;
    ub = (ub + 0x7fffu + ((ub >> 16) & 1u)) >> 16;
    return ua | (ub << 16);
}
__device__ __forceinline__ void upk(unsigned u, float& lo, float& hi) {
    lo = __uint_as_float(u << 16);
    hi = __uint_as_float(u & 0xffff0000u);
}

// ---------- pass A: per-bucket edge histogram ----------
__global__ void bucket_count(const int* __restrict__ dst, int* __restrict__ bcount) {
    __shared__ int h[NB];
    for (int t = threadIdx.x; t < NB; t += blockDim.x) h[t] = 0;
    __syncthreads();
    int stride = gridDim.x * blockDim.x;
    for (int e = blockIdx.x * blockDim.x + threadIdx.x; e < N_EDGES; e += stride)
        atomicAdd(&h[__builtin_nontemporal_load(&dst[e]) >> BSH], 1);
    __syncthreads();
    for (int t = threadIdx.x; t < NB; t += blockDim.x)
        if (h[t]) atomicAdd(&bcount[t], h[t]);
}

// ---------- pass B: exclusive scan over buckets ----------
__global__ void bucket_scan(const int* __restrict__ bcount,
                            int* __restrict__ bstart, int* __restrict__ bcursor) {
    __shared__ int s[NB];
    int t = threadIdx.x;
    if (t < NB) s[t] = bcount[t];
    __syncthreads();
    if (t == 0) {
        int acc = 0;
        for (int i = 0; i < NB; i++) { int c = s[i]; s[i] = acc; acc += c; }
    }
    __syncthreads();
    if (t < NB) { bstart[t] = s[t]; bcursor[t] = s[t]; }
    if (t == 0) bstart[NB] = N_EDGES;
}

// ---------- pass C: scatter edges into bucket segments, packed (src<<8)|dstLocal ----------
__global__ void bucket_scatter(const int* __restrict__ src, const int* __restrict__ dst,
                               int* __restrict__ bcursor, unsigned int* __restrict__ packed) {
    __shared__ int h[NB];
    __shared__ int wp[NB];
    for (int t = threadIdx.x; t < NB; t += blockDim.x) h[t] = 0;
    __syncthreads();
    int per = (N_EDGES + gridDim.x - 1) / gridDim.x;
    int e0 = blockIdx.x * per;
    int e1 = e0 + per; if (e1 > N_EDGES) e1 = N_EDGES;
    for (int e = e0 + threadIdx.x; e < e1; e += blockDim.x)
        atomicAdd(&h[__builtin_nontemporal_load(&dst[e]) >> BSH], 1);
    __syncthreads();
    for (int t = threadIdx.x; t < NB; t += blockDim.x) {
        int c = h[t];
        wp[t] = c ? atomicAdd(&bcursor[t], c) : 0;
    }
    __syncthreads();
    for (int e = e0 + threadIdx.x; e < e1; e += blockDim.x) {
        int d = __builtin_nontemporal_load(&dst[e]);
        int s = __builtin_nontemporal_load(&src[e]);
        int b = d >> BSH;
        int r = atomicAdd(&wp[b], 1);
        packed[r] = ((unsigned)s << BSH) | (unsigned)(d & (BNODES - 1));
    }
}

// ---------- pass C2: within each bucket, counting-sort edges by src group ----------
__global__ void __launch_bounds__(256)
bucket_sort2(const unsigned* __restrict__ pin, const int* __restrict__ bstart,
             unsigned* __restrict__ pout) {
    __shared__ int cnt[NGRP];
    __shared__ int cur[NGRP];
    int b = blockIdx.x;
    int e0 = bstart[b], e1 = bstart[b + 1];
    int tid = threadIdx.x;
    if (tid < NGRP) cnt[tid] = 0;
    __syncthreads();
    for (int e = e0 + tid; e < e1; e += 256)
        atomicAdd(&cnt[__builtin_nontemporal_load(&pin[e]) >> (BSH + GSH)], 1);
    __syncthreads();
    if (tid == 0) {
        int acc = 0;
        for (int g = 0; g < NGRP; g++) { int c = cnt[g]; cur[g] = acc; acc += c; }
    }
    __syncthreads();
    for (int e = e0 + tid; e < e1; e += 256) {
        unsigned p = __builtin_nontemporal_load(&pin[e]);
        int slot = atomicAdd(&cur[p >> (BSH + GSH)], 1);
        pout[e0 + slot] = p;
    }
}

// ---------- y = x @ w1_1 -> split bf16 tables ----------
__global__ void xform_kernel(const float* __restrict__ x,
                             const float* __restrict__ w1,   // [16][10]
                             unsigned* __restrict__ oA,      // [N][4] u32 (8 bf16)
                             unsigned* __restrict__ oB) {    // [N] u32 (2 bf16)
    int i = blockIdx.x * blockDim.x + threadIdx.x;
    if (i >= N_NODES) return;
    float xi[NFEAT];
    const float4* xr = reinterpret_cast<const float4*>(x + (size_t)i * NFEAT);
#pragma unroll
    for (int q = 0; q < 4; q++) {
        float4 v = xr[q];
        xi[q*4+0] = v.x; xi[q*4+1] = v.y; xi[q*4+2] = v.z; xi[q*4+3] = v.w;
    }
    float o[DIM];
#pragma unroll
    for (int j = 0; j < DIM; j++) {
        float s = 0.f;
#pragma unroll
        for (int f = 0; f < NFEAT; f++) s += xi[f] * w1[f * DIM + j];
        o[j] = s;
    }
    uint4 qa = make_uint4(pkbf(o[0], o[1]), pkbf(o[2], o[3]),
                          pkbf(o[4], o[5]), pkbf(o[6], o[7]));
    *(uint4*)(oA + 4 * (size_t)i) = qa;
    oB[i] = pkbf(o[8], o[9]);
}

// ---------- pass D: per-bucket LDS aggregation + MLP + pool ----------
template <bool FIRST>
__global__ void __launch_bounds__(LTB, 8)
gin_layer(const unsigned* __restrict__ tA,            // [N][4] u32
          const unsigned* __restrict__ tB,            // [N] u32
          const unsigned* __restrict__ packed,
          const int* __restrict__ bstart,
          const float* __restrict__ w1, const float* __restrict__ b1,
          const float* __restrict__ w2, const float* __restrict__ b2,
          const int* __restrict__ batch,
          unsigned* __restrict__ oA, unsigned* __restrict__ oB,
          float* __restrict__ pooled) {               // [G][10] layer slice
    __shared__ float agg[BNODES][DIMP];
    __shared__ float wts[2][DIM * DIM];
    __shared__ float bias[2][DIM];
    __shared__ int gidb[BNODES];
    int tid = threadIdx.x;
    int b = blockIdx.x;
    int n0 = b << BSH;
    int nn = N_NODES - n0; if (nn > BNODES) nn = BNODES;

    for (int t = tid; t < BNODES * DIMP; t += LTB) ((float*)agg)[t] = 0.f;
    if (!FIRST) for (int t = tid; t < DIM * DIM; t += LTB) wts[0][t] = w1[t];
    for (int t = tid; t < DIM * DIM; t += LTB) wts[1][t] = w2[t];
    if (tid < DIM) { bias[0][tid] = b1[tid]; bias[1][tid] = b2[tid]; }
    __syncthreads();

    int e0 = bstart[b], e1 = bstart[b + 1];
    int e = e0 + tid;
    for (; e + LTB < e1; e += 2 * LTB) {
        unsigned p0 = __builtin_nontemporal_load(&packed[e]);
        unsigned p1 = __builtin_nontemporal_load(&packed[e + LTB]);
        int s0 = p0 >> BSH, d0 = p0 & (BNODES - 1);
        int s1 = p1 >> BSH, d1 = p1 & (BNODES - 1);
        uint4 a0 = *(const uint4*)(tA + 4 * (size_t)s0);
        unsigned w0 = tB[s0];
        uint4 a1 = *(const uint4*)(tA + 4 * (size_t)s1);
        unsigned w1b = tB[s1];
        float v[DIM];
        upk(a0.x, v[0], v[1]); upk(a0.y, v[2], v[3]);
        upk(a0.z, v[4], v[5]); upk(a0.w, v[6], v[7]);
        upk(w0,  v[8], v[9]);
#pragma unroll
        for (int j = 0; j < DIM; j++) atomicAdd(&agg[d0][j], v[j]);
        upk(a1.x, v[0], v[1]); upk(a1.y, v[2], v[3]);
        upk(a1.z, v[4], v[5]); upk(a1.w, v[6], v[7]);
        upk(w1b, v[8], v[9]);
#pragma unroll
        for (int j = 0; j < DIM; j++) atomicAdd(&agg[d1][j], v[j]);
    }
    if (e < e1) {
        unsigned p0 = __builtin_nontemporal_load(&packed[e]);
        int s0 = p0 >> BSH, d0 = p0 & (BNODES - 1);
        uint4 a0 = *(const uint4*)(tA + 4 * (size_t)s0);
        unsigned w0 = tB[s0];
        float v[DIM];
        upk(a0.x, v[0], v[1]); upk(a0.y, v[2], v[3]);
        upk(a0.z, v[4], v[5]); upk(a0.w, v[6], v[7]);
        upk(w0,  v[8], v[9]);
#pragma unroll
        for (int j = 0; j < DIM; j++) atomicAdd(&agg[d0][j], v[j]);
    }
    __syncthreads();

    float hv[DIM];
    int i = n0 + tid;
    if (tid < nn) {
        uint4 a4 = *(const uint4*)(tA + 4 * (size_t)i);
        unsigned bw = tB[i];
        float own[DIM];
        upk(a4.x, own[0], own[1]); upk(a4.y, own[2], own[3]);
        upk(a4.z, own[4], own[5]); upk(a4.w, own[6], own[7]);
        upk(bw, own[8], own[9]);
        float z[DIM];
#pragma unroll
        for (int j = 0; j < DIM; j++) z[j] = own[j] + agg[tid][j];
        float t1[DIM];
        if (FIRST) {
#pragma unroll
            for (int j = 0; j < DIM; j++) { float v = z[j] + bias[0][j]; t1[j] = v > 0.f ? v : 0.f; }
        } else {
#pragma unroll
            for (int j = 0; j < DIM; j++) {
                float s = bias[0][j];
#pragma unroll
                for (int f = 0; f < DIM; f++) s += z[f] * wts[0][f * DIM + j];
                t1[j] = s > 0.f ? s : 0.f;
            }
        }
#pragma unroll
        for (int j = 0; j < DIM; j++) {
            float s = bias[1][j];
#pragma unroll
            for (int f = 0; f < DIM; f++) s += t1[f] * wts[1][f * DIM + j];
            hv[j] = s > 0.f ? s : 0.f;
        }
        uint4 qa = make_uint4(pkbf(hv[0], hv[1]), pkbf(hv[2], hv[3]),
                              pkbf(hv[4], hv[5]), pkbf(hv[6], hv[7]));
        *(uint4*)(oA + 4 * (size_t)i) = qa;
        oB[i] = pkbf(hv[8], hv[9]);
        gidb[tid] = batch[i];
    }
    __syncthreads();
    if (tid < nn) {
#pragma unroll
        for (int j = 0; j < DIM; j++) agg[tid][j] = hv[j];   // f32 pool stage
    }
    __syncthreads();

    // per-wave run-length pool reduction (batch sorted -> few runs); 32 nodes/wave
    int wv = tid >> 6, lane = tid & 63;
    int s0 = wv << 5;
    if (lane < DIM && s0 < nn) {
        int send = s0 + 32; if (send > nn) send = nn;
        int cg = gidb[s0];
        float acc = agg[s0][lane];
        for (int n = s0 + 1; n < send; n++) {
            int g = gidb[n];
            float v = agg[n][lane];
            if (g == cg) acc += v;
            else { atomicAdd(&pooled[cg * DIM + lane], acc); cg = g; acc = v; }
        }
        atomicAdd(&pooled[cg * DIM + lane], acc);
    }
}

// ---------- readout: counts via binary search on sorted batch ----------
__global__ void final_kernel(const float* __restrict__ pooled,  // [5][G][10]
                             const int* __restrict__ batch,
                             const float* __restrict__ lw,      // [5][10]
                             float* __restrict__ out) {
    int g = blockIdx.x * blockDim.x + threadIdx.x;
    if (g >= NGRAPH) return;
    int lo = 0, hi = N_NODES;
    while (lo < hi) { int m = (lo + hi) >> 1; if (batch[m] < g) lo = m + 1; else hi = m; }
    int a = lo;
    hi = N_NODES;
    while (lo < hi) { int m = (lo + hi) >> 1; if (batch[m] < g + 1) lo = m + 1; else hi = m; }
    float c = (float)(lo - a);
    float inv = 1.0f / (c > 1.f ? c : 1.f);
    float s = 0.f;
#pragma unroll
    for (int l = 0; l < 5; l++) {
        float d = 0.f;
#pragma unroll
        for (int j = 0; j < DIM; j++)
            d += pooled[(size_t)l * NGRAPH * DIM + (size_t)g * DIM + j] * lw[l * DIM + j];
        s += d * inv;
    }
    out[g] = 1.0f / (1.0f + expf(-s));
}

extern "C" void kernel_launch(void* const* d_in, const int* in_sizes, int n_in,
                              void* d_out, int out_size, void* d_ws, size_t ws_size,
                              hipStream_t stream) {
    const float* x    = (const float*)d_in[0];
    const int*   ei   = (const int*)d_in[1];
    const int*   batch= (const int*)d_in[2];
    const float* w1_1 = (const float*)d_in[3];
    const float* b1_1 = (const float*)d_in[4];
    const float* w2_1 = (const float*)d_in[5];
    const float* b2_1 = (const float*)d_in[6];
    const float* ws1  = (const float*)d_in[7];   // [4][10][10]
    const float* bs1  = (const float*)d_in[8];   // [4][10]
    const float* ws2  = (const float*)d_in[9];   // [4][10][10]
    const float* bs2  = (const float*)d_in[10];  // [4][10]
    const float* lw   = (const float*)d_in[11];  // [5][10]
    float* out = (float*)d_out;

    const int* src = ei;
    const int* dst = ei + N_EDGES;

    // ---- workspace layout (u32 units; 16B alignment for uint4 tables) ----
    int* bcount   = (int*)d_ws;                         // [NB]
    int* bstart   = bcount + NB;                        // [NB+1]
    int* bcursor  = bstart + NB + 1;                    // [NB]
    unsigned* packed  = (unsigned*)d_ws + 2348;         // [E]
    unsigned* packed2 = packed + N_EDGES;               // [E]
    unsigned* tA0 = packed2 + N_EDGES;                  // [N*4]
    unsigned* tB0 = tA0 + (size_t)N_NODES * 4;          // [N]
    unsigned* tA1 = tB0 + N_NODES;                      // [N*4]
    unsigned* tB1 = tA1 + (size_t)N_NODES * 4;          // [N]
    float* pooled = (float*)(tB1 + N_NODES);            // [5][G][10]
    size_t needed = (size_t)((char*)(pooled + 5 * NGRAPH * DIM) - (char*)d_ws);
    if (needed > ws_size) return;  // loud failure (output stays zero)

    const int TB = 256;
    int nblocks = (N_NODES + TB - 1) / TB;
    int gblocks = (NGRAPH + TB - 1) / TB;

    hipMemsetAsync(bcount, 0, NB * sizeof(int), stream);
    hipMemsetAsync(pooled, 0, (size_t)5 * NGRAPH * DIM * sizeof(float), stream);

    // ---- two-level semi-sort: by dst bucket, then by src group ----
    bucket_count<<<384, TB, 0, stream>>>(dst, bcount);
    bucket_scan<<<1, 1024, 0, stream>>>(bcount, bstart, bcursor);
    bucket_scatter<<<CBLK, TB, 0, stream>>>(src, dst, bcursor, packed);
    bucket_sort2<<<NB, TB, 0, stream>>>(packed, bstart, packed2);

    // ---- layer 1 (pre-applied w1) ----
    xform_kernel<<<nblocks, TB, 0, stream>>>(x, w1_1, tA0, tB0);
    gin_layer<true><<<NB, LTB, 0, stream>>>(tA0, tB0, packed2, bstart,
        nullptr, b1_1, w2_1, b2_1, batch, tA1, tB1, pooled);

    // ---- layers 2..5 (ping-pong) ----
    unsigned *iA = tA1, *iB = tB1, *oA = tA0, *oB = tB0;
    for (int l = 0; l < 4; l++) {
        gin_layer<false><<<NB, LTB, 0, stream>>>(iA, iB, packed2, bstart,
            ws1 + (size_t)l * DIM * DIM, bs1 + (size_t)l * DIM,
            ws2 + (size_t)l * DIM * DIM, bs2 + (size_t)l * DIM,
            batch, oA, oB, pooled + (size_t)(l + 1) * NGRAPH * DIM);
        unsigned* t;
        t = iA; iA = oA; oA = t;
        t = iB; iB = oB; oB = t;
    }

    // ---- readout ----
    final_kernel<<<gblocks, TB, 0, stream>>>(pooled, batch, lw, out);
}

// Round 6
// 1012.467 us; speedup vs baseline: 1.9183x; 1.9183x over previous
//
#include <hip/hip_runtime.h>
#include <math.h>

#define N_NODES 200000
#define N_EDGES 5000000
#define NFEAT 16
#define DIM 10
#define NGRAPH 1000
#define BSH 8            // 256 nodes per dst bucket
#define BNODES 256
#define NB ((N_NODES + BNODES - 1) / BNODES)   // 782
#define CBLK 320
#define RSTRIDE 8        // row stride in u32 (32B): word k holds dims 2k,2k+1 (k<5)

// pack two f32 -> two bf16 (RNE) in one u32
__device__ __forceinline__ unsigned pkbf(float a, float b) {
    unsigned ua = __float_as_uint(a), ub = __float_as_uint(b);
    ua = (ua + 0x7fffu + ((ua >> 16) & 1u)) >> 16;
    ub = (ub + 0x7fffu + ((ub >> 16) & 1u)) >> 16;
    return ua | (ub << 16);
}

// ---------- pass A: per-bucket edge histogram ----------
__global__ void bucket_count(const int* __restrict__ dst, int* __restrict__ bcount) {
    __shared__ int h[NB];
    for (int t = threadIdx.x; t < NB; t += blockDim.x) h[t] = 0;
    __syncthreads();
    int stride = gridDim.x * blockDim.x;
    for (int e = blockIdx.x * blockDim.x + threadIdx.x; e < N_EDGES; e += stride)
        atomicAdd(&h[__builtin_nontemporal_load(&dst[e]) >> BSH], 1);
    __syncthreads();
    for (int t = threadIdx.x; t < NB; t += blockDim.x)
        if (h[t]) atomicAdd(&bcount[t], h[t]);
}

// ---------- pass B: exclusive scan over buckets ----------
__global__ void bucket_scan(const int* __restrict__ bcount,
                            int* __restrict__ bstart, int* __restrict__ bcursor) {
    __shared__ int s[NB];
    int t = threadIdx.x;
    if (t < NB) s[t] = bcount[t];
    __syncthreads();
    if (t == 0) {
        int acc = 0;
        for (int i = 0; i < NB; i++) { int c = s[i]; s[i] = acc; acc += c; }
    }
    __syncthreads();
    if (t < NB) { bstart[t] = s[t]; bcursor[t] = s[t]; }
    if (t == 0) bstart[NB] = N_EDGES;
}

// ---------- pass C: scatter edges into bucket segments, packed (src<<8)|dstLocal ----------
__global__ void bucket_scatter(const int* __restrict__ src, const int* __restrict__ dst,
                               int* __restrict__ bcursor, unsigned int* __restrict__ packed) {
    __shared__ int h[NB];
    __shared__ int wp[NB];
    for (int t = threadIdx.x; t < NB; t += blockDim.x) h[t] = 0;
    __syncthreads();
    int per = (N_EDGES + gridDim.x - 1) / gridDim.x;
    int e0 = blockIdx.x * per;
    int e1 = e0 + per; if (e1 > N_EDGES) e1 = N_EDGES;
    for (int e = e0 + threadIdx.x; e < e1; e += blockDim.x)
        atomicAdd(&h[__builtin_nontemporal_load(&dst[e]) >> BSH], 1);
    __syncthreads();
    for (int t = threadIdx.x; t < NB; t += blockDim.x) {
        int c = h[t];
        wp[t] = c ? atomicAdd(&bcursor[t], c) : 0;
    }
    __syncthreads();
    for (int e = e0 + threadIdx.x; e < e1; e += blockDim.x) {
        int d = __builtin_nontemporal_load(&dst[e]);
        int s = __builtin_nontemporal_load(&src[e]);
        int b = d >> BSH;
        int r = atomicAdd(&wp[b], 1);
        packed[r] = ((unsigned)s << BSH) | (unsigned)(d & (BNODES - 1));
    }
}

// ---------- pass C2: per-bucket counting sort by dstLocal -> per-node CSR ----------
__global__ void __launch_bounds__(BNODES)
node_sort(const unsigned* __restrict__ pin, const int* __restrict__ bstart,
          unsigned* __restrict__ ecol, int* __restrict__ rowstart) {
    __shared__ int cnt[BNODES];
    __shared__ int cur[BNODES];
    int b = blockIdx.x;
    int e0 = bstart[b], e1 = bstart[b + 1];
    int tid = threadIdx.x;
    cnt[tid] = 0;
    __syncthreads();
    for (int e = e0 + tid; e < e1; e += BNODES)
        atomicAdd(&cnt[__builtin_nontemporal_load(&pin[e]) & (BNODES - 1)], 1);
    __syncthreads();
    if (tid == 0) {
        int acc = 0;
        for (int t = 0; t < BNODES; ++t) { int c = cnt[t]; cur[t] = acc; acc += c; }
    }
    __syncthreads();
    int n0 = b << BSH;
    if (n0 + tid < N_NODES) rowstart[n0 + tid] = e0 + cur[tid];
    if (b == 0 && tid == 0) rowstart[N_NODES] = N_EDGES;
    for (int e = e0 + tid; e < e1; e += BNODES) {
        unsigned p = __builtin_nontemporal_load(&pin[e]);
        int slot = atomicAdd(&cur[p & (BNODES - 1)], 1);
        ecol[e0 + slot] = p >> BSH;     // src id, grouped by dst node
    }
}

// ---------- y = x @ w1_1 -> bf16 rows, 32B stride ----------
__global__ void xform_kernel(const float* __restrict__ x,
                             const float* __restrict__ w1,   // [16][10]
                             unsigned* __restrict__ tout) {  // [N][8] u32
    int i = blockIdx.x * blockDim.x + threadIdx.x;
    if (i >= N_NODES) return;
    float xi[NFEAT];
    const float4* xr = reinterpret_cast<const float4*>(x + (size_t)i * NFEAT);
#pragma unroll
    for (int q = 0; q < 4; q++) {
        float4 v = xr[q];
        xi[q*4+0] = v.x; xi[q*4+1] = v.y; xi[q*4+2] = v.z; xi[q*4+3] = v.w;
    }
    float o[DIM];
#pragma unroll
    for (int j = 0; j < DIM; j++) {
        float s = 0.f;
#pragma unroll
        for (int f = 0; f < NFEAT; f++) s += xi[f] * w1[f * DIM + j];
        o[j] = s;
    }
    uint4 qa = make_uint4(pkbf(o[0], o[1]), pkbf(o[2], o[3]),
                          pkbf(o[4], o[5]), pkbf(o[6], o[7]));
    *(uint4*)(tout + (size_t)RSTRIDE * i) = qa;
    tout[(size_t)RSTRIDE * i + 4] = pkbf(o[8], o[9]);
}

// ---------- fused gather + MLP + pool: 16 lanes per node, dim-owner layout ----------
template <bool FIRST>
__global__ void __launch_bounds__(256)
gin_gather2(const unsigned* __restrict__ tin,     // [N][8] u32 bf16 rows
            const int* __restrict__ rowstart,     // [N+1]
            const unsigned* __restrict__ ecol,    // [E] src ids (dst-sorted)
            const float* __restrict__ w1, const float* __restrict__ b1,
            const float* __restrict__ w2, const float* __restrict__ b2,
            const int* __restrict__ batch,
            unsigned* __restrict__ tout,
            float* __restrict__ pooled) {
    __shared__ float hp[16][DIM];
    __shared__ int gid[16];
    int tid = threadIdx.x;
    int grp = tid >> 4;              // node slot in block (0..15)
    int j = tid & 15;                // lane in group; lane j owns dim j (j<10)
    int lane = tid & 63;
    int base = lane & 48;            // group base within wave
    int i = blockIdx.x * 16 + grp;   // grid exact: 12500 * 16 = 200000

    int r0 = rowstart[i];
    int r1 = rowstart[i + 1];

    int word = j >> 1;
    bool hi = (j & 1);
    unsigned wown = (j < DIM) ? tin[(size_t)i * RSTRIDE + word] : 0u;
    float acc = (j < DIM) ? (hi ? __uint_as_float(wown & 0xffff0000u)
                               : __uint_as_float(wown << 16)) : 0.f;

    for (int e0 = r0; e0 < r1; e0 += 16) {
        int idx = e0 + j;
        unsigned sv = (idx < r1) ? ecol[idx] : 0u;
        int cnt = r1 - e0;
        if (cnt >= 16) {
#pragma unroll
            for (int k = 0; k < 16; ++k) {
                unsigned s = __shfl(sv, base + k, 64);
                if (j < DIM) {
                    unsigned w = tin[(size_t)s * RSTRIDE + word];
                    acc += hi ? __uint_as_float(w & 0xffff0000u)
                              : __uint_as_float(w << 16);
                }
            }
        } else {
            for (int k = 0; k < cnt; ++k) {
                unsigned s = __shfl(sv, base + k, 64);
                if (j < DIM) {
                    unsigned w = tin[(size_t)s * RSTRIDE + word];
                    acc += hi ? __uint_as_float(w & 0xffff0000u)
                              : __uint_as_float(w << 16);
                }
            }
        }
    }

    float t1v;
    if (FIRST) {
        t1v = (j < DIM) ? (acc + b1[j]) : 0.f;
    } else {
        float s1 = (j < DIM) ? b1[j] : 0.f;
#pragma unroll
        for (int f = 0; f < DIM; ++f) {
            float zf = __shfl(acc, base + f, 64);
            if (j < DIM) s1 += zf * w1[f * DIM + j];
        }
        t1v = s1;
    }
    t1v = t1v > 0.f ? t1v : 0.f;

    float s2 = (j < DIM) ? b2[j] : 0.f;
#pragma unroll
    for (int f = 0; f < DIM; ++f) {
        float tf = __shfl(t1v, base + f, 64);
        if (j < DIM) s2 += tf * w2[f * DIM + j];
    }
    float hv = s2 > 0.f ? s2 : 0.f;

    // pack pairs: lane j (even, <10) combines hv(j), hv(j+1) into word j/2
    float hnext = __shfl(hv, base + ((j + 1) & 15), 64);
    if (j < DIM && !hi)
        tout[(size_t)i * RSTRIDE + word] = pkbf(hv, hnext);

    if (j < DIM) hp[grp][j] = hv;
    if (j == 0) gid[grp] = batch[i];
    __syncthreads();

    // run-length block pool reduction (batch sorted -> few runs)
    if (tid < DIM) {
        int cg = gid[0];
        float s = hp[0][tid];
        for (int n = 1; n < 16; ++n) {
            int g = gid[n];
            float v = hp[n][tid];
            if (g == cg) s += v;
            else { atomicAdd(&pooled[cg * DIM + tid], s); cg = g; s = v; }
        }
        atomicAdd(&pooled[cg * DIM + tid], s);
    }
}

// ---------- readout: counts via binary search on sorted batch ----------
__global__ void final_kernel(const float* __restrict__ pooled,  // [5][G][10]
                             const int* __restrict__ batch,
                             const float* __restrict__ lw,      // [5][10]
                             float* __restrict__ out) {
    int g = blockIdx.x * blockDim.x + threadIdx.x;
    if (g >= NGRAPH) return;
    int lo = 0, hi = N_NODES;
    while (lo < hi) { int m = (lo + hi) >> 1; if (batch[m] < g) lo = m + 1; else hi = m; }
    int a = lo;
    hi = N_NODES;
    while (lo < hi) { int m = (lo + hi) >> 1; if (batch[m] < g + 1) lo = m + 1; else hi = m; }
    float c = (float)(lo - a);
    float inv = 1.0f / (c > 1.f ? c : 1.f);
    float s = 0.f;
#pragma unroll
    for (int l = 0; l < 5; l++) {
        float d = 0.f;
#pragma unroll
        for (int j = 0; j < DIM; j++)
            d += pooled[(size_t)l * NGRAPH * DIM + (size_t)g * DIM + j] * lw[l * DIM + j];
        s += d * inv;
    }
    out[g] = 1.0f / (1.0f + expf(-s));
}

extern "C" void kernel_launch(void* const* d_in, const int* in_sizes, int n_in,
                              void* d_out, int out_size, void* d_ws, size_t ws_size,
                              hipStream_t stream) {
    const float* x    = (const float*)d_in[0];
    const int*   ei   = (const int*)d_in[1];
    const int*   batch= (const int*)d_in[2];
    const float* w1_1 = (const float*)d_in[3];
    const float* b1_1 = (const float*)d_in[4];
    const float* w2_1 = (const float*)d_in[5];
    const float* b2_1 = (const float*)d_in[6];
    const float* ws1  = (const float*)d_in[7];   // [4][10][10]
    const float* bs1  = (const float*)d_in[8];   // [4][10]
    const float* ws2  = (const float*)d_in[9];   // [4][10][10]
    const float* bs2  = (const float*)d_in[10];  // [4][10]
    const float* lw   = (const float*)d_in[11];  // [5][10]
    float* out = (float*)d_out;

    const int* src = ei;
    const int* dst = ei + N_EDGES;

    // ---- workspace layout (u32 units; 16B aligned sections) ----
    int* bcount   = (int*)d_ws;                         // [NB]         @0
    int* bstart   = bcount + NB;                        // [NB+1]
    int* bcursor  = bstart + NB + 1;                    // [NB]         (ends 2347)
    int* rowstart = (int*)d_ws + 2352;                  // [N+1]        @2352
    unsigned* packed = (unsigned*)d_ws + 202356;        // [E]  (dead after node_sort; reused as tA1)
    unsigned* tA1    = packed;                          // [N*8] overlay
    unsigned* ecol   = packed + N_EDGES;                // [E]
    unsigned* tA0    = ecol + N_EDGES;                  // [N*8]
    float* pooled = (float*)(tA0 + (size_t)N_NODES * RSTRIDE); // [5][G][10]
    size_t needed = (size_t)((char*)(pooled + 5 * NGRAPH * DIM) - (char*)d_ws);
    if (needed > ws_size) return;  // loud failure (output stays zero)

    const int TB = 256;
    int nblocks = (N_NODES + TB - 1) / TB;
    int gblocks = (NGRAPH + TB - 1) / TB;

    hipMemsetAsync(bcount, 0, NB * sizeof(int), stream);
    hipMemsetAsync(pooled, 0, (size_t)5 * NGRAPH * DIM * sizeof(float), stream);

    // ---- build per-node CSR: bucket sort then per-bucket counting sort ----
    bucket_count<<<384, TB, 0, stream>>>(dst, bcount);
    bucket_scan<<<1, 1024, 0, stream>>>(bcount, bstart, bcursor);
    bucket_scatter<<<CBLK, TB, 0, stream>>>(src, dst, bcursor, packed);
    node_sort<<<NB, BNODES, 0, stream>>>(packed, bstart, ecol, rowstart);

    // ---- layer 1 (pre-applied w1) ----
    xform_kernel<<<nblocks, TB, 0, stream>>>(x, w1_1, tA0);
    gin_gather2<true><<<N_NODES / 16, TB, 0, stream>>>(tA0, rowstart, ecol,
        nullptr, b1_1, w2_1, b2_1, batch, tA1, pooled);

    // ---- layers 2..5 (ping-pong tA1 <-> tA0) ----
    unsigned *tin = tA1, *tout2 = tA0;
    for (int l = 0; l < 4; l++) {
        gin_gather2<false><<<N_NODES / 16, TB, 0, stream>>>(tin, rowstart, ecol,
            ws1 + (size_t)l * DIM * DIM, bs1 + (size_t)l * DIM,
            ws2 + (size_t)l * DIM * DIM, bs2 + (size_t)l * DIM,
            batch, tout2, pooled + (size_t)(l + 1) * NGRAPH * DIM);
        unsigned* t = tin; tin = tout2; tout2 = t;
    }

    // ---- readout ----
    final_kernel<<<gblocks, TB, 0, stream>>>(pooled, batch, lw, out);
}

// Round 7
// 882.023 us; speedup vs baseline: 2.2021x; 1.1479x over previous
//
#include <hip/hip_runtime.h>
#include <math.h>

#define N_NODES 200000
#define N_EDGES 5000000
#define NFEAT 16
#define DIM 10
#define NGRAPH 1000
#define BSH 8            // 256 nodes per dst bucket
#define BNODES 256
#define NB ((N_NODES + BNODES - 1) / BNODES)   // 782
#define CBLK 320
#define RSTRIDE 8        // row stride in u32 (32B): word k holds dims 2k,2k+1 (k<5)

// pack two f32 -> two bf16 (RNE) in one u32
__device__ __forceinline__ unsigned pkbf(float a, float b) {
    unsigned ua = __float_as_uint(a), ub = __float_as_uint(b);
    ua = (ua + 0x7fffu + ((ua >> 16) & 1u)) >> 16;
    ub = (ub + 0x7fffu + ((ub >> 16) & 1u)) >> 16;
    return ua | (ub << 16);
}

// ---------- pass A: per-bucket edge histogram ----------
__global__ void bucket_count(const int* __restrict__ dst, int* __restrict__ bcount) {
    __shared__ int h[NB];
    for (int t = threadIdx.x; t < NB; t += blockDim.x) h[t] = 0;
    __syncthreads();
    int stride = gridDim.x * blockDim.x;
    for (int e = blockIdx.x * blockDim.x + threadIdx.x; e < N_EDGES; e += stride)
        atomicAdd(&h[__builtin_nontemporal_load(&dst[e]) >> BSH], 1);
    __syncthreads();
    for (int t = threadIdx.x; t < NB; t += blockDim.x)
        if (h[t]) atomicAdd(&bcount[t], h[t]);
}

// ---------- pass B: exclusive scan over buckets ----------
__global__ void bucket_scan(const int* __restrict__ bcount,
                            int* __restrict__ bstart, int* __restrict__ bcursor) {
    __shared__ int s[NB];
    int t = threadIdx.x;
    if (t < NB) s[t] = bcount[t];
    __syncthreads();
    if (t == 0) {
        int acc = 0;
        for (int i = 0; i < NB; i++) { int c = s[i]; s[i] = acc; acc += c; }
    }
    __syncthreads();
    if (t < NB) { bstart[t] = s[t]; bcursor[t] = s[t]; }
    if (t == 0) bstart[NB] = N_EDGES;
}

// ---------- pass C: scatter edges into bucket segments, packed (src<<8)|dstLocal ----------
__global__ void bucket_scatter(const int* __restrict__ src, const int* __restrict__ dst,
                               int* __restrict__ bcursor, unsigned int* __restrict__ packed) {
    __shared__ int h[NB];
    __shared__ int wp[NB];
    for (int t = threadIdx.x; t < NB; t += blockDim.x) h[t] = 0;
    __syncthreads();
    int per = (N_EDGES + gridDim.x - 1) / gridDim.x;
    int e0 = blockIdx.x * per;
    int e1 = e0 + per; if (e1 > N_EDGES) e1 = N_EDGES;
    for (int e = e0 + threadIdx.x; e < e1; e += blockDim.x)
        atomicAdd(&h[__builtin_nontemporal_load(&dst[e]) >> BSH], 1);
    __syncthreads();
    for (int t = threadIdx.x; t < NB; t += blockDim.x) {
        int c = h[t];
        wp[t] = c ? atomicAdd(&bcursor[t], c) : 0;
    }
    __syncthreads();
    for (int e = e0 + threadIdx.x; e < e1; e += blockDim.x) {
        int d = __builtin_nontemporal_load(&dst[e]);
        int s = __builtin_nontemporal_load(&src[e]);
        int b = d >> BSH;
        int r = atomicAdd(&wp[b], 1);
        packed[r] = ((unsigned)s << BSH) | (unsigned)(d & (BNODES - 1));
    }
}

// ---------- pass C2: per-bucket counting sort by dstLocal -> per-node CSR ----------
__global__ void __launch_bounds__(BNODES)
node_sort(const unsigned* __restrict__ pin, const int* __restrict__ bstart,
          unsigned* __restrict__ ecol, int* __restrict__ rowstart) {
    __shared__ int cnt[BNODES];
    __shared__ int cur[BNODES];
    int b = blockIdx.x;
    int e0 = bstart[b], e1 = bstart[b + 1];
    int tid = threadIdx.x;
    cnt[tid] = 0;
    __syncthreads();
    for (int e = e0 + tid; e < e1; e += BNODES)
        atomicAdd(&cnt[__builtin_nontemporal_load(&pin[e]) & (BNODES - 1)], 1);
    __syncthreads();
    if (tid == 0) {
        int acc = 0;
        for (int t = 0; t < BNODES; ++t) { int c = cnt[t]; cur[t] = acc; acc += c; }
    }
    __syncthreads();
    int n0 = b << BSH;
    if (n0 + tid < N_NODES) rowstart[n0 + tid] = e0 + cur[tid];
    if (b == 0 && tid == 0) rowstart[N_NODES] = N_EDGES;
    for (int e = e0 + tid; e < e1; e += BNODES) {
        unsigned p = __builtin_nontemporal_load(&pin[e]);
        int slot = atomicAdd(&cur[p & (BNODES - 1)], 1);
        ecol[e0 + slot] = p >> BSH;     // src id, grouped by dst node
    }
}

// ---------- y = x @ w1_1 -> bf16 rows, 32B stride ----------
__global__ void xform_kernel(const float* __restrict__ x,
                             const float* __restrict__ w1,   // [16][10]
                             unsigned* __restrict__ tout) {  // [N][8] u32
    int i = blockIdx.x * blockDim.x + threadIdx.x;
    if (i >= N_NODES) return;
    float xi[NFEAT];
    const float4* xr = reinterpret_cast<const float4*>(x + (size_t)i * NFEAT);
#pragma unroll
    for (int q = 0; q < 4; q++) {
        float4 v = xr[q];
        xi[q*4+0] = v.x; xi[q*4+1] = v.y; xi[q*4+2] = v.z; xi[q*4+3] = v.w;
    }
    float o[DIM];
#pragma unroll
    for (int j = 0; j < DIM; j++) {
        float s = 0.f;
#pragma unroll
        for (int f = 0; f < NFEAT; f++) s += xi[f] * w1[f * DIM + j];
        o[j] = s;
    }
    uint4 qa = make_uint4(pkbf(o[0], o[1]), pkbf(o[2], o[3]),
                          pkbf(o[4], o[5]), pkbf(o[6], o[7]));
    *(uint4*)(tout + (size_t)RSTRIDE * i) = qa;
    tout[(size_t)RSTRIDE * i + 4] = pkbf(o[8], o[9]);
}

// ---------- fused gather + MLP + pool: 16 lanes per node, dim-owner layout ----------
// Inner loop restructured for ILP: 16 explicit in-flight loads (static-index
// vals[16], two unrolled passes) + next-chunk sv prefetch. launch_bounds(256,8)
// keeps 8 waves/SIMD while allowing ~48 VGPRs for load destinations.
template <bool FIRST>
__global__ void __launch_bounds__(256, 8)
gin_gather2(const unsigned* __restrict__ tin,     // [N][8] u32 bf16 rows
            const int* __restrict__ rowstart,     // [N+1]
            const unsigned* __restrict__ ecol,    // [E] src ids (dst-sorted)
            const float* __restrict__ w1, const float* __restrict__ b1,
            const float* __restrict__ w2, const float* __restrict__ b2,
            const int* __restrict__ batch,
            unsigned* __restrict__ tout,
            float* __restrict__ pooled) {
    __shared__ float hp[16][DIM];
    __shared__ int gid[16];
    int tid = threadIdx.x;
    int grp = tid >> 4;              // node slot in block (0..15)
    int j = tid & 15;                // lane in group; lane j owns dim j (j<10)
    int lane = tid & 63;
    int base = lane & 48;            // group base within wave
    int i = blockIdx.x * 16 + grp;   // grid exact: 12500 * 16 = 200000

    int r0 = rowstart[i];
    int r1 = rowstart[i + 1];

    int word = j >> 1;
    bool hi = (j & 1);
    const unsigned* tw = tin + word;   // lane-constant word offset
    unsigned wown = (j < DIM) ? tw[(size_t)i * RSTRIDE] : 0u;
    float acc = (j < DIM) ? (hi ? __uint_as_float(wown & 0xffff0000u)
                               : __uint_as_float(wown << 16)) : 0.f;

    // prefetch first chunk's src ids
    unsigned sv = (r0 + j < r1) ? ecol[r0 + j] : 0u;

    for (int e0 = r0; e0 < r1; e0 += 16) {
        // prefetch next chunk's src ids before consuming current
        unsigned svn = (e0 + 16 + j < r1) ? ecol[e0 + 16 + j] : 0u;
        int cnt = r1 - e0;             // >=1; may exceed 16 (clamped by k<16 unroll)
        float vals[16];
        bool act = (j < DIM);
#pragma unroll
        for (int k = 0; k < 16; ++k) {
            unsigned s = __shfl(sv, base + k, 64);
            float v = 0.f;
            if (k < cnt && act) {
                unsigned w = tw[(size_t)s * RSTRIDE];
                v = hi ? __uint_as_float(w & 0xffff0000u)
                       : __uint_as_float(w << 16);
            }
            vals[k] = v;
        }
#pragma unroll
        for (int k = 0; k < 16; ++k) acc += vals[k];
        sv = svn;
    }

    float t1v;
    if (FIRST) {
        t1v = (j < DIM) ? (acc + b1[j]) : 0.f;
    } else {
        float s1 = (j < DIM) ? b1[j] : 0.f;
#pragma unroll
        for (int f = 0; f < DIM; ++f) {
            float zf = __shfl(acc, base + f, 64);
            if (j < DIM) s1 += zf * w1[f * DIM + j];
        }
        t1v = s1;
    }
    t1v = t1v > 0.f ? t1v : 0.f;

    float s2 = (j < DIM) ? b2[j] : 0.f;
#pragma unroll
    for (int f = 0; f < DIM; ++f) {
        float tf = __shfl(t1v, base + f, 64);
        if (j < DIM) s2 += tf * w2[f * DIM + j];
    }
    float hv = s2 > 0.f ? s2 : 0.f;

    // pack pairs: lane j (even, <10) combines hv(j), hv(j+1) into word j/2
    float hnext = __shfl(hv, base + ((j + 1) & 15), 64);
    if (j < DIM && !hi)
        tout[(size_t)i * RSTRIDE + word] = pkbf(hv, hnext);

    if (j < DIM) hp[grp][j] = hv;
    if (j == 0) gid[grp] = batch[i];
    __syncthreads();

    // run-length block pool reduction (batch sorted -> few runs)
    if (tid < DIM) {
        int cg = gid[0];
        float s = hp[0][tid];
        for (int n = 1; n < 16; ++n) {
            int g = gid[n];
            float v = hp[n][tid];
            if (g == cg) s += v;
            else { atomicAdd(&pooled[cg * DIM + tid], s); cg = g; s = v; }
        }
        atomicAdd(&pooled[cg * DIM + tid], s);
    }
}

// ---------- readout: counts via binary search on sorted batch ----------
__global__ void final_kernel(const float* __restrict__ pooled,  // [5][G][10]
                             const int* __restrict__ batch,
                             const float* __restrict__ lw,      // [5][10]
                             float* __restrict__ out) {
    int g = blockIdx.x * blockDim.x + threadIdx.x;
    if (g >= NGRAPH) return;
    int lo = 0, hi = N_NODES;
    while (lo < hi) { int m = (lo + hi) >> 1; if (batch[m] < g) lo = m + 1; else hi = m; }
    int a = lo;
    hi = N_NODES;
    while (lo < hi) { int m = (lo + hi) >> 1; if (batch[m] < g + 1) lo = m + 1; else hi = m; }
    float c = (float)(lo - a);
    float inv = 1.0f / (c > 1.f ? c : 1.f);
    float s = 0.f;
#pragma unroll
    for (int l = 0; l < 5; l++) {
        float d = 0.f;
#pragma unroll
        for (int j = 0; j < DIM; j++)
            d += pooled[(size_t)l * NGRAPH * DIM + (size_t)g * DIM + j] * lw[l * DIM + j];
        s += d * inv;
    }
    out[g] = 1.0f / (1.0f + expf(-s));
}

extern "C" void kernel_launch(void* const* d_in, const int* in_sizes, int n_in,
                              void* d_out, int out_size, void* d_ws, size_t ws_size,
                              hipStream_t stream) {
    const float* x    = (const float*)d_in[0];
    const int*   ei   = (const int*)d_in[1];
    const int*   batch= (const int*)d_in[2];
    const float* w1_1 = (const float*)d_in[3];
    const float* b1_1 = (const float*)d_in[4];
    const float* w2_1 = (const float*)d_in[5];
    const float* b2_1 = (const float*)d_in[6];
    const float* ws1  = (const float*)d_in[7];   // [4][10][10]
    const float* bs1  = (const float*)d_in[8];   // [4][10]
    const float* ws2  = (const float*)d_in[9];   // [4][10][10]
    const float* bs2  = (const float*)d_in[10];  // [4][10]
    const float* lw   = (const float*)d_in[11];  // [5][10]
    float* out = (float*)d_out;

    const int* src = ei;
    const int* dst = ei + N_EDGES;

    // ---- workspace layout (u32 units; 16B aligned sections) ----
    int* bcount   = (int*)d_ws;                         // [NB]         @0
    int* bstart   = bcount + NB;                        // [NB+1]
    int* bcursor  = bstart + NB + 1;                    // [NB]         (ends 2347)
    int* rowstart = (int*)d_ws + 2352;                  // [N+1]        @2352
    unsigned* packed = (unsigned*)d_ws + 202356;        // [E]  (dead after node_sort; reused as tA1)
    unsigned* tA1    = packed;                          // [N*8] overlay
    unsigned* ecol   = packed + N_EDGES;                // [E]
    unsigned* tA0    = ecol + N_EDGES;                  // [N*8]
    float* pooled = (float*)(tA0 + (size_t)N_NODES * RSTRIDE); // [5][G][10]
    size_t needed = (size_t)((char*)(pooled + 5 * NGRAPH * DIM) - (char*)d_ws);
    if (needed > ws_size) return;  // loud failure (output stays zero)

    const int TB = 256;
    int nblocks = (N_NODES + TB - 1) / TB;
    int gblocks = (NGRAPH + TB - 1) / TB;

    hipMemsetAsync(bcount, 0, NB * sizeof(int), stream);
    hipMemsetAsync(pooled, 0, (size_t)5 * NGRAPH * DIM * sizeof(float), stream);

    // ---- build per-node CSR: bucket sort then per-bucket counting sort ----
    bucket_count<<<384, TB, 0, stream>>>(dst, bcount);
    bucket_scan<<<1, 1024, 0, stream>>>(bcount, bstart, bcursor);
    bucket_scatter<<<CBLK, TB, 0, stream>>>(src, dst, bcursor, packed);
    node_sort<<<NB, BNODES, 0, stream>>>(packed, bstart, ecol, rowstart);

    // ---- layer 1 (pre-applied w1) ----
    xform_kernel<<<nblocks, TB, 0, stream>>>(x, w1_1, tA0);
    gin_gather2<true><<<N_NODES / 16, TB, 0, stream>>>(tA0, rowstart, ecol,
        nullptr, b1_1, w2_1, b2_1, batch, tA1, pooled);

    // ---- layers 2..5 (ping-pong tA1 <-> tA0) ----
    unsigned *tin = tA1, *tout2 = tA0;
    for (int l = 0; l < 4; l++) {
        gin_gather2<false><<<N_NODES / 16, TB, 0, stream>>>(tin, rowstart, ecol,
            ws1 + (size_t)l * DIM * DIM, bs1 + (size_t)l * DIM,
            ws2 + (size_t)l * DIM * DIM, bs2 + (size_t)l * DIM,
            batch, tout2, pooled + (size_t)(l + 1) * NGRAPH * DIM);
        unsigned* t = tin; tin = tout2; tout2 = t;
    }

    // ---- readout ----
    final_kernel<<<gblocks, TB, 0, stream>>>(pooled, batch, lw, out);
}

// Round 8
// 793.581 us; speedup vs baseline: 2.4475x; 1.1114x over previous
//
#include <hip/hip_runtime.h>
#include <math.h>

#define N_NODES 200000
#define N_EDGES 5000000
#define NFEAT 16
#define DIM 10
#define NGRAPH 1000
#define BSH 8            // 256 nodes per dst bucket
#define BNODES 256
#define NB ((N_NODES + BNODES - 1) / BNODES)   // 782
#define CBLK 128         // scatter blocks: longer per-bucket write runs
#define RSTRIDE 5        // row stride in u32 (20B): word k holds dims 2k,2k+1 -> 4.0MB table, L2-fit

// pack two f32 -> two bf16 (RNE) in one u32
__device__ __forceinline__ unsigned pkbf(float a, float b) {
    unsigned ua = __float_as_uint(a), ub = __float_as_uint(b);
    ua = (ua + 0x7fffu + ((ua >> 16) & 1u)) >> 16;
    ub = (ub + 0x7fffu + ((ub >> 16) & 1u)) >> 16;
    return ua | (ub << 16);
}

// ---------- pass A: per-bucket edge histogram ----------
__global__ void bucket_count(const int* __restrict__ dst, int* __restrict__ bcount) {
    __shared__ int h[NB];
    for (int t = threadIdx.x; t < NB; t += blockDim.x) h[t] = 0;
    __syncthreads();
    int stride = gridDim.x * blockDim.x;
    for (int e = blockIdx.x * blockDim.x + threadIdx.x; e < N_EDGES; e += stride)
        atomicAdd(&h[__builtin_nontemporal_load(&dst[e]) >> BSH], 1);
    __syncthreads();
    for (int t = threadIdx.x; t < NB; t += blockDim.x)
        if (h[t]) atomicAdd(&bcount[t], h[t]);
}

// ---------- pass B: exclusive scan over buckets ----------
__global__ void bucket_scan(const int* __restrict__ bcount,
                            int* __restrict__ bstart, int* __restrict__ bcursor) {
    __shared__ int s[NB];
    int t = threadIdx.x;
    if (t < NB) s[t] = bcount[t];
    __syncthreads();
    if (t == 0) {
        int acc = 0;
        for (int i = 0; i < NB; i++) { int c = s[i]; s[i] = acc; acc += c; }
    }
    __syncthreads();
    if (t < NB) { bstart[t] = s[t]; bcursor[t] = s[t]; }
    if (t == 0) bstart[NB] = N_EDGES;
}

// ---------- pass C: scatter edges into bucket segments, packed (src<<8)|dstLocal ----------
__global__ void bucket_scatter(const int* __restrict__ src, const int* __restrict__ dst,
                               int* __restrict__ bcursor, unsigned int* __restrict__ packed) {
    __shared__ int h[NB];
    __shared__ int wp[NB];
    for (int t = threadIdx.x; t < NB; t += blockDim.x) h[t] = 0;
    __syncthreads();
    int per = (N_EDGES + gridDim.x - 1) / gridDim.x;
    int e0 = blockIdx.x * per;
    int e1 = e0 + per; if (e1 > N_EDGES) e1 = N_EDGES;
    for (int e = e0 + threadIdx.x; e < e1; e += blockDim.x)
        atomicAdd(&h[__builtin_nontemporal_load(&dst[e]) >> BSH], 1);
    __syncthreads();
    for (int t = threadIdx.x; t < NB; t += blockDim.x) {
        int c = h[t];
        wp[t] = c ? atomicAdd(&bcursor[t], c) : 0;
    }
    __syncthreads();
    for (int e = e0 + threadIdx.x; e < e1; e += blockDim.x) {
        int d = __builtin_nontemporal_load(&dst[e]);
        int s = __builtin_nontemporal_load(&src[e]);
        int b = d >> BSH;
        int r = atomicAdd(&wp[b], 1);
        packed[r] = ((unsigned)s << BSH) | (unsigned)(d & (BNODES - 1));
    }
}

// ---------- pass C2: per-bucket counting sort by dstLocal -> per-node CSR ----------
__global__ void __launch_bounds__(BNODES)
node_sort(const unsigned* __restrict__ pin, const int* __restrict__ bstart,
          unsigned* __restrict__ ecol, int* __restrict__ rowstart) {
    __shared__ int cnt[BNODES];
    __shared__ int cur[BNODES];
    int b = blockIdx.x;
    int e0 = bstart[b], e1 = bstart[b + 1];
    int tid = threadIdx.x;
    cnt[tid] = 0;
    __syncthreads();
    for (int e = e0 + tid; e < e1; e += BNODES)
        atomicAdd(&cnt[__builtin_nontemporal_load(&pin[e]) & (BNODES - 1)], 1);
    __syncthreads();
    if (tid == 0) {
        int acc = 0;
        for (int t = 0; t < BNODES; ++t) { int c = cnt[t]; cur[t] = acc; acc += c; }
    }
    __syncthreads();
    int n0 = b << BSH;
    if (n0 + tid < N_NODES) rowstart[n0 + tid] = e0 + cur[tid];
    if (b == 0 && tid == 0) rowstart[N_NODES] = N_EDGES;
    for (int e = e0 + tid; e < e1; e += BNODES) {
        unsigned p = __builtin_nontemporal_load(&pin[e]);
        int slot = atomicAdd(&cur[p & (BNODES - 1)], 1);
        ecol[e0 + slot] = p >> BSH;     // src id, grouped by dst node
    }
}

// ---------- y = x @ w1_1 -> bf16 rows, 20B stride ----------
__global__ void xform_kernel(const float* __restrict__ x,
                             const float* __restrict__ w1,   // [16][10]
                             unsigned* __restrict__ tout) {  // [N][5] u32
    int i = blockIdx.x * blockDim.x + threadIdx.x;
    if (i >= N_NODES) return;
    float xi[NFEAT];
    const float4* xr = reinterpret_cast<const float4*>(x + (size_t)i * NFEAT);
#pragma unroll
    for (int q = 0; q < 4; q++) {
        float4 v = xr[q];
        xi[q*4+0] = v.x; xi[q*4+1] = v.y; xi[q*4+2] = v.z; xi[q*4+3] = v.w;
    }
    float o[DIM];
#pragma unroll
    for (int j = 0; j < DIM; j++) {
        float s = 0.f;
#pragma unroll
        for (int f = 0; f < NFEAT; f++) s += xi[f] * w1[f * DIM + j];
        o[j] = s;
    }
#pragma unroll
    for (int k = 0; k < 5; k++)
        __builtin_nontemporal_store(pkbf(o[2*k], o[2*k+1]),
                                    &tout[(size_t)RSTRIDE * i + k]);
}

// ---------- fused gather + MLP + pool: 16 lanes per node, dim-owner layout ----------
// 16-deep in-flight loads (static-index vals[16]) + next-chunk sv prefetch.
// Table rows are 20B (4.0MB total -> per-XCD-L2-resident). ecol stream nt-loaded,
// output table nt-stored so writes don't evict the input table from L2.
template <bool FIRST>
__global__ void __launch_bounds__(256, 8)
gin_gather2(const unsigned* __restrict__ tin,     // [N][5] u32 bf16 rows
            const int* __restrict__ rowstart,     // [N+1]
            const unsigned* __restrict__ ecol,    // [E] src ids (dst-sorted)
            const float* __restrict__ w1, const float* __restrict__ b1,
            const float* __restrict__ w2, const float* __restrict__ b2,
            const int* __restrict__ batch,
            unsigned* __restrict__ tout,
            float* __restrict__ pooled) {
    __shared__ float hp[16][DIM];
    __shared__ int gid[16];
    int tid = threadIdx.x;
    int grp = tid >> 4;              // node slot in block (0..15)
    int j = tid & 15;                // lane in group; lane j owns dim j (j<10)
    int lane = tid & 63;
    int base = lane & 48;            // group base within wave
    int i = blockIdx.x * 16 + grp;   // grid exact: 12500 * 16 = 200000

    int r0 = rowstart[i];
    int r1 = rowstart[i + 1];

    int word = j >> 1;
    bool hi = (j & 1);
    const unsigned* tw = tin + word;   // lane-constant word offset
    unsigned wown = (j < DIM) ? tw[(size_t)i * RSTRIDE] : 0u;
    float acc = (j < DIM) ? (hi ? __uint_as_float(wown & 0xffff0000u)
                               : __uint_as_float(wown << 16)) : 0.f;

    // prefetch first chunk's src ids
    unsigned sv = (r0 + j < r1) ? __builtin_nontemporal_load(&ecol[r0 + j]) : 0u;

    for (int e0 = r0; e0 < r1; e0 += 16) {
        unsigned svn = (e0 + 16 + j < r1) ? __builtin_nontemporal_load(&ecol[e0 + 16 + j]) : 0u;
        int cnt = r1 - e0;
        float vals[16];
        bool act = (j < DIM);
#pragma unroll
        for (int k = 0; k < 16; ++k) {
            unsigned s = __shfl(sv, base + k, 64);
            float v = 0.f;
            if (k < cnt && act) {
                unsigned w = tw[(size_t)s * RSTRIDE];
                v = hi ? __uint_as_float(w & 0xffff0000u)
                       : __uint_as_float(w << 16);
            }
            vals[k] = v;
        }
#pragma unroll
        for (int k = 0; k < 16; ++k) acc += vals[k];
        sv = svn;
    }

    float t1v;
    if (FIRST) {
        t1v = (j < DIM) ? (acc + b1[j]) : 0.f;
    } else {
        float s1 = (j < DIM) ? b1[j] : 0.f;
#pragma unroll
        for (int f = 0; f < DIM; ++f) {
            float zf = __shfl(acc, base + f, 64);
            if (j < DIM) s1 += zf * w1[f * DIM + j];
        }
        t1v = s1;
    }
    t1v = t1v > 0.f ? t1v : 0.f;

    float s2 = (j < DIM) ? b2[j] : 0.f;
#pragma unroll
    for (int f = 0; f < DIM; ++f) {
        float tf = __shfl(t1v, base + f, 64);
        if (j < DIM) s2 += tf * w2[f * DIM + j];
    }
    float hv = s2 > 0.f ? s2 : 0.f;

    // pack pairs: lane j (even, <10) combines hv(j), hv(j+1) into word j/2
    float hnext = __shfl(hv, base + ((j + 1) & 15), 64);
    if (j < DIM && !hi)
        __builtin_nontemporal_store(pkbf(hv, hnext), &tout[(size_t)i * RSTRIDE + word]);

    if (j < DIM) hp[grp][j] = hv;
    if (j == 0) gid[grp] = batch[i];
    __syncthreads();

    // run-length block pool reduction (batch sorted -> few runs)
    if (tid < DIM) {
        int cg = gid[0];
        float s = hp[0][tid];
        for (int n = 1; n < 16; ++n) {
            int g = gid[n];
            float v = hp[n][tid];
            if (g == cg) s += v;
            else { atomicAdd(&pooled[cg * DIM + tid], s); cg = g; s = v; }
        }
        atomicAdd(&pooled[cg * DIM + tid], s);
    }
}

// ---------- readout: counts via binary search on sorted batch ----------
__global__ void final_kernel(const float* __restrict__ pooled,  // [5][G][10]
                             const int* __restrict__ batch,
                             const float* __restrict__ lw,      // [5][10]
                             float* __restrict__ out) {
    int g = blockIdx.x * blockDim.x + threadIdx.x;
    if (g >= NGRAPH) return;
    int lo = 0, hi = N_NODES;
    while (lo < hi) { int m = (lo + hi) >> 1; if (batch[m] < g) lo = m + 1; else hi = m; }
    int a = lo;
    hi = N_NODES;
    while (lo < hi) { int m = (lo + hi) >> 1; if (batch[m] < g + 1) lo = m + 1; else hi = m; }
    float c = (float)(lo - a);
    float inv = 1.0f / (c > 1.f ? c : 1.f);
    float s = 0.f;
#pragma unroll
    for (int l = 0; l < 5; l++) {
        float d = 0.f;
#pragma unroll
        for (int j = 0; j < DIM; j++)
            d += pooled[(size_t)l * NGRAPH * DIM + (size_t)g * DIM + j] * lw[l * DIM + j];
        s += d * inv;
    }
    out[g] = 1.0f / (1.0f + expf(-s));
}

extern "C" void kernel_launch(void* const* d_in, const int* in_sizes, int n_in,
                              void* d_out, int out_size, void* d_ws, size_t ws_size,
                              hipStream_t stream) {
    const float* x    = (const float*)d_in[0];
    const int*   ei   = (const int*)d_in[1];
    const int*   batch= (const int*)d_in[2];
    const float* w1_1 = (const float*)d_in[3];
    const float* b1_1 = (const float*)d_in[4];
    const float* w2_1 = (const float*)d_in[5];
    const float* b2_1 = (const float*)d_in[6];
    const float* ws1  = (const float*)d_in[7];   // [4][10][10]
    const float* bs1  = (const float*)d_in[8];   // [4][10]
    const float* ws2  = (const float*)d_in[9];   // [4][10][10]
    const float* bs2  = (const float*)d_in[10];  // [4][10]
    const float* lw   = (const float*)d_in[11];  // [5][10]
    float* out = (float*)d_out;

    const int* src = ei;
    const int* dst = ei + N_EDGES;

    // ---- workspace layout (u32 units) ----
    int* bcount   = (int*)d_ws;                         // [NB]         @0
    int* bstart   = bcount + NB;                        // [NB+1]
    int* bcursor  = bstart + NB + 1;                    // [NB]         (ends 2347)
    int* rowstart = (int*)d_ws + 2352;                  // [N+1]        @2352
    unsigned* packed = (unsigned*)d_ws + 202356;        // [E]  (dead after node_sort; reused as tA1)
    unsigned* tA1    = packed;                          // [N*5] overlay
    unsigned* ecol   = packed + N_EDGES;                // [E]
    unsigned* tA0    = ecol + N_EDGES;                  // [N*5]
    float* pooled = (float*)(tA0 + (size_t)N_NODES * RSTRIDE); // [5][G][10]
    size_t needed = (size_t)((char*)(pooled + 5 * NGRAPH * DIM) - (char*)d_ws);
    if (needed > ws_size) return;  // loud failure (output stays zero)

    const int TB = 256;
    int nblocks = (N_NODES + TB - 1) / TB;
    int gblocks = (NGRAPH + TB - 1) / TB;

    hipMemsetAsync(bcount, 0, NB * sizeof(int), stream);
    hipMemsetAsync(pooled, 0, (size_t)5 * NGRAPH * DIM * sizeof(float), stream);

    // ---- build per-node CSR: bucket sort then per-bucket counting sort ----
    bucket_count<<<384, TB, 0, stream>>>(dst, bcount);
    bucket_scan<<<1, 1024, 0, stream>>>(bcount, bstart, bcursor);
    bucket_scatter<<<CBLK, TB, 0, stream>>>(src, dst, bcursor, packed);
    node_sort<<<NB, BNODES, 0, stream>>>(packed, bstart, ecol, rowstart);

    // ---- layer 1 (pre-applied w1) ----
    xform_kernel<<<nblocks, TB, 0, stream>>>(x, w1_1, tA0);
    gin_gather2<true><<<N_NODES / 16, TB, 0, stream>>>(tA0, rowstart, ecol,
        nullptr, b1_1, w2_1, b2_1, batch, tA1, pooled);

    // ---- layers 2..5 (ping-pong tA1 <-> tA0) ----
    unsigned *tin = tA1, *tout2 = tA0;
    for (int l = 0; l < 4; l++) {
        gin_gather2<false><<<N_NODES / 16, TB, 0, stream>>>(tin, rowstart, ecol,
            ws1 + (size_t)l * DIM * DIM, bs1 + (size_t)l * DIM,
            ws2 + (size_t)l * DIM * DIM, bs2 + (size_t)l * DIM,
            batch, tout2, pooled + (size_t)(l + 1) * NGRAPH * DIM);
        unsigned* t = tin; tin = tout2; tout2 = t;
    }

    // ---- readout ----
    final_kernel<<<gblocks, TB, 0, stream>>>(pooled, batch, lw, out);
}

// Round 9
// 702.016 us; speedup vs baseline: 2.7667x; 1.1304x over previous
//
#include <hip/hip_runtime.h>
#include <math.h>

#define N_NODES 200000
#define N_EDGES 5000000
#define NFEAT 16
#define DIM 10
#define NGRAPH 1000
#define BSH 8            // 256 nodes per dst bucket
#define BNODES 256
#define NB ((N_NODES + BNODES - 1) / BNODES)   // 782
#define NBLK 512         // hist/scatter blocks
#define STB 512          // hist/scatter block size
#define RSTRIDE 5        // row stride in u32 (20B) -> 4.0MB table, per-XCD-L2-fit

// pack two f32 -> two bf16 (RNE) in one u32
__device__ __forceinline__ unsigned pkbf(float a, float b) {
    unsigned ua = __float_as_uint(a), ub = __float_as_uint(b);
    ua = (ua + 0x7fffu + ((ua >> 16) & 1u)) >> 16;
    ub = (ub + 0x7fffu + ((ub >> 16) & 1u)) >> 16;
    return ua | (ub << 16);
}

// ---------- pass 1: per-block bucket histogram -> histg[block][NB] ----------
__global__ void __launch_bounds__(STB)
khist(const int* __restrict__ dst, unsigned* __restrict__ histg) {
    __shared__ int h[NB];
    for (int t = threadIdx.x; t < NB; t += STB) h[t] = 0;
    __syncthreads();
    int per = (N_EDGES + NBLK - 1) / NBLK;
    int e0 = blockIdx.x * per;
    int e1 = e0 + per; if (e1 > N_EDGES) e1 = N_EDGES;
    int e = e0 + threadIdx.x;
    for (; e + 7 * STB < e1; e += 8 * STB) {
        int d0 = __builtin_nontemporal_load(&dst[e]);
        int d1 = __builtin_nontemporal_load(&dst[e + STB]);
        int d2 = __builtin_nontemporal_load(&dst[e + 2 * STB]);
        int d3 = __builtin_nontemporal_load(&dst[e + 3 * STB]);
        int d4 = __builtin_nontemporal_load(&dst[e + 4 * STB]);
        int d5 = __builtin_nontemporal_load(&dst[e + 5 * STB]);
        int d6 = __builtin_nontemporal_load(&dst[e + 6 * STB]);
        int d7 = __builtin_nontemporal_load(&dst[e + 7 * STB]);
        atomicAdd(&h[d0 >> BSH], 1); atomicAdd(&h[d1 >> BSH], 1);
        atomicAdd(&h[d2 >> BSH], 1); atomicAdd(&h[d3 >> BSH], 1);
        atomicAdd(&h[d4 >> BSH], 1); atomicAdd(&h[d5 >> BSH], 1);
        atomicAdd(&h[d6 >> BSH], 1); atomicAdd(&h[d7 >> BSH], 1);
    }
    for (; e < e1; e += STB)
        atomicAdd(&h[__builtin_nontemporal_load(&dst[e]) >> BSH], 1);
    __syncthreads();
    for (int t = threadIdx.x; t < NB; t += STB)
        histg[(size_t)blockIdx.x * NB + t] = h[t];
}

// ---------- pass 2: hierarchical scan: histg -> per-(block,bucket) bases; bstart ----------
__global__ void __launch_bounds__(1024)
kscan(unsigned* __restrict__ histg, int* __restrict__ bstart) {
    __shared__ int tot[NB];
    __shared__ int bst[NB];
    int t = threadIdx.x;
    if (t < NB) {
        int s = 0;
        for (int blk = 0; blk < NBLK; ++blk) s += histg[(size_t)blk * NB + t];
        tot[t] = s;
    }
    __syncthreads();
    if (t == 0) {
        int acc = 0;
        for (int i = 0; i < NB; ++i) { int c = tot[i]; bst[i] = acc; acc += c; }
    }
    __syncthreads();
    if (t < NB) {
        int run = bst[t];
        for (int blk = 0; blk < NBLK; ++blk) {
            unsigned c = histg[(size_t)blk * NB + t];
            histg[(size_t)blk * NB + t] = run;
            run += c;
        }
        bstart[t] = bst[t];
    }
    if (t == 0) bstart[NB] = N_EDGES;
}

// ---------- pass 3: single-pass scatter from precomputed bases ----------
__global__ void __launch_bounds__(STB)
kscatter(const int* __restrict__ src, const int* __restrict__ dst,
         const unsigned* __restrict__ histg, unsigned* __restrict__ packed) {
    __shared__ int wp[NB];
    for (int t = threadIdx.x; t < NB; t += STB)
        wp[t] = histg[(size_t)blockIdx.x * NB + t];
    __syncthreads();
    int per = (N_EDGES + NBLK - 1) / NBLK;
    int e0 = blockIdx.x * per;
    int e1 = e0 + per; if (e1 > N_EDGES) e1 = N_EDGES;
    int e = e0 + threadIdx.x;
    for (; e + 7 * STB < e1; e += 8 * STB) {
        int d[8], s[8];
#pragma unroll
        for (int k = 0; k < 8; ++k) {
            d[k] = __builtin_nontemporal_load(&dst[e + k * STB]);
            s[k] = __builtin_nontemporal_load(&src[e + k * STB]);
        }
#pragma unroll
        for (int k = 0; k < 8; ++k) {
            int r = atomicAdd(&wp[d[k] >> BSH], 1);
            packed[r] = ((unsigned)s[k] << BSH) | (unsigned)(d[k] & (BNODES - 1));
        }
    }
    for (; e < e1; e += STB) {
        int dv = __builtin_nontemporal_load(&dst[e]);
        int sv = __builtin_nontemporal_load(&src[e]);
        int r = atomicAdd(&wp[dv >> BSH], 1);
        packed[r] = ((unsigned)sv << BSH) | (unsigned)(dv & (BNODES - 1));
    }
}

// ---------- pass 4: per-bucket counting sort by dstLocal -> per-node CSR ----------
__global__ void __launch_bounds__(BNODES)
node_sort(const unsigned* __restrict__ pin, const int* __restrict__ bstart,
          unsigned* __restrict__ ecol, int* __restrict__ rowstart) {
    __shared__ int cnt[BNODES];
    __shared__ int cur[BNODES];
    int b = blockIdx.x;
    int e0 = bstart[b], e1 = bstart[b + 1];
    int tid = threadIdx.x;
    cnt[tid] = 0;
    __syncthreads();
    int e = e0 + tid;
    for (; e + 7 * BNODES < e1; e += 8 * BNODES) {
        unsigned p[8];
#pragma unroll
        for (int k = 0; k < 8; ++k) p[k] = __builtin_nontemporal_load(&pin[e + k * BNODES]);
#pragma unroll
        for (int k = 0; k < 8; ++k) atomicAdd(&cnt[p[k] & (BNODES - 1)], 1);
    }
    for (; e < e1; e += BNODES)
        atomicAdd(&cnt[__builtin_nontemporal_load(&pin[e]) & (BNODES - 1)], 1);
    __syncthreads();
    if (tid == 0) {
        int acc = 0;
        for (int t = 0; t < BNODES; ++t) { int c = cnt[t]; cur[t] = acc; acc += c; }
    }
    __syncthreads();
    int n0 = b << BSH;
    if (n0 + tid < N_NODES) rowstart[n0 + tid] = e0 + cur[tid];
    if (b == 0 && tid == 0) rowstart[N_NODES] = N_EDGES;
    e = e0 + tid;
    for (; e + 3 * BNODES < e1; e += 4 * BNODES) {
        unsigned p[4];
#pragma unroll
        for (int k = 0; k < 4; ++k) p[k] = __builtin_nontemporal_load(&pin[e + k * BNODES]);
#pragma unroll
        for (int k = 0; k < 4; ++k) {
            int slot = atomicAdd(&cur[p[k] & (BNODES - 1)], 1);
            ecol[e0 + slot] = p[k] >> BSH;
        }
    }
    for (; e < e1; e += BNODES) {
        unsigned p = __builtin_nontemporal_load(&pin[e]);
        int slot = atomicAdd(&cur[p & (BNODES - 1)], 1);
        ecol[e0 + slot] = p >> BSH;
    }
}

// ---------- y = x @ w1_1 -> bf16 rows, 20B stride ----------
__global__ void xform_kernel(const float* __restrict__ x,
                             const float* __restrict__ w1,   // [16][10]
                             unsigned* __restrict__ tout) {  // [N][5] u32
    int i = blockIdx.x * blockDim.x + threadIdx.x;
    if (i >= N_NODES) return;
    float xi[NFEAT];
    const float4* xr = reinterpret_cast<const float4*>(x + (size_t)i * NFEAT);
#pragma unroll
    for (int q = 0; q < 4; q++) {
        float4 v = xr[q];
        xi[q*4+0] = v.x; xi[q*4+1] = v.y; xi[q*4+2] = v.z; xi[q*4+3] = v.w;
    }
    float o[DIM];
#pragma unroll
    for (int j = 0; j < DIM; j++) {
        float s = 0.f;
#pragma unroll
        for (int f = 0; f < NFEAT; f++) s += xi[f] * w1[f * DIM + j];
        o[j] = s;
    }
#pragma unroll
    for (int k = 0; k < 5; k++)
        __builtin_nontemporal_store(pkbf(o[2*k], o[2*k+1]),
                                    &tout[(size_t)RSTRIDE * i + k]);
}

// ---------- fused gather + MLP + pool: 16 lanes per node, dim-owner layout ----------
template <bool FIRST>
__global__ void __launch_bounds__(256, 8)
gin_gather2(const unsigned* __restrict__ tin,     // [N][5] u32 bf16 rows
            const int* __restrict__ rowstart,     // [N+1]
            const unsigned* __restrict__ ecol,    // [E] src ids (dst-sorted)
            const float* __restrict__ w1, const float* __restrict__ b1,
            const float* __restrict__ w2, const float* __restrict__ b2,
            const int* __restrict__ batch,
            unsigned* __restrict__ tout,
            float* __restrict__ pooled) {
    __shared__ float hp[16][DIM];
    __shared__ int gid[16];
    int tid = threadIdx.x;
    int grp = tid >> 4;              // node slot in block (0..15)
    int j = tid & 15;                // lane in group; lane j owns dim j (j<10)
    int lane = tid & 63;
    int base = lane & 48;            // group base within wave
    int i = blockIdx.x * 16 + grp;   // grid exact: 12500 * 16 = 200000

    int r0 = rowstart[i];
    int r1 = rowstart[i + 1];

    int word = j >> 1;
    bool hi = (j & 1);
    const unsigned* tw = tin + word;   // lane-constant word offset
    unsigned wown = (j < DIM) ? tw[(size_t)i * RSTRIDE] : 0u;
    float acc = (j < DIM) ? (hi ? __uint_as_float(wown & 0xffff0000u)
                               : __uint_as_float(wown << 16)) : 0.f;

    unsigned sv = (r0 + j < r1) ? __builtin_nontemporal_load(&ecol[r0 + j]) : 0u;

    for (int e0 = r0; e0 < r1; e0 += 16) {
        unsigned svn = (e0 + 16 + j < r1) ? __builtin_nontemporal_load(&ecol[e0 + 16 + j]) : 0u;
        int cnt = r1 - e0;
        float vals[16];
        bool act = (j < DIM);
#pragma unroll
        for (int k = 0; k < 16; ++k) {
            unsigned s = __shfl(sv, base + k, 64);
            float v = 0.f;
            if (k < cnt && act) {
                unsigned w = tw[(size_t)s * RSTRIDE];
                v = hi ? __uint_as_float(w & 0xffff0000u)
                       : __uint_as_float(w << 16);
            }
            vals[k] = v;
        }
#pragma unroll
        for (int k = 0; k < 16; ++k) acc += vals[k];
        sv = svn;
    }

    float t1v;
    if (FIRST) {
        t1v = (j < DIM) ? (acc + b1[j]) : 0.f;
    } else {
        float s1 = (j < DIM) ? b1[j] : 0.f;
#pragma unroll
        for (int f = 0; f < DIM; ++f) {
            float zf = __shfl(acc, base + f, 64);
            if (j < DIM) s1 += zf * w1[f * DIM + j];
        }
        t1v = s1;
    }
    t1v = t1v > 0.f ? t1v : 0.f;

    float s2 = (j < DIM) ? b2[j] : 0.f;
#pragma unroll
    for (int f = 0; f < DIM; ++f) {
        float tf = __shfl(t1v, base + f, 64);
        if (j < DIM) s2 += tf * w2[f * DIM + j];
    }
    float hv = s2 > 0.f ? s2 : 0.f;

    float hnext = __shfl(hv, base + ((j + 1) & 15), 64);
    if (j < DIM && !hi)
        __builtin_nontemporal_store(pkbf(hv, hnext), &tout[(size_t)i * RSTRIDE + word]);

    if (j < DIM) hp[grp][j] = hv;
    if (j == 0) gid[grp] = batch[i];
    __syncthreads();

    if (tid < DIM) {
        int cg = gid[0];
        float s = hp[0][tid];
        for (int n = 1; n < 16; ++n) {
            int g = gid[n];
            float v = hp[n][tid];
            if (g == cg) s += v;
            else { atomicAdd(&pooled[cg * DIM + tid], s); cg = g; s = v; }
        }
        atomicAdd(&pooled[cg * DIM + tid], s);
    }
}

// ---------- readout: counts via binary search on sorted batch ----------
__global__ void final_kernel(const float* __restrict__ pooled,  // [5][G][10]
                             const int* __restrict__ batch,
                             const float* __restrict__ lw,      // [5][10]
                             float* __restrict__ out) {
    int g = blockIdx.x * blockDim.x + threadIdx.x;
    if (g >= NGRAPH) return;
    int lo = 0, hi = N_NODES;
    while (lo < hi) { int m = (lo + hi) >> 1; if (batch[m] < g) lo = m + 1; else hi = m; }
    int a = lo;
    hi = N_NODES;
    while (lo < hi) { int m = (lo + hi) >> 1; if (batch[m] < g + 1) lo = m + 1; else hi = m; }
    float c = (float)(lo - a);
    float inv = 1.0f / (c > 1.f ? c : 1.f);
    float s = 0.f;
#pragma unroll
    for (int l = 0; l < 5; l++) {
        float d = 0.f;
#pragma unroll
        for (int j = 0; j < DIM; j++)
            d += pooled[(size_t)l * NGRAPH * DIM + (size_t)g * DIM + j] * lw[l * DIM + j];
        s += d * inv;
    }
    out[g] = 1.0f / (1.0f + expf(-s));
}

extern "C" void kernel_launch(void* const* d_in, const int* in_sizes, int n_in,
                              void* d_out, int out_size, void* d_ws, size_t ws_size,
                              hipStream_t stream) {
    const float* x    = (const float*)d_in[0];
    const int*   ei   = (const int*)d_in[1];
    const int*   batch= (const int*)d_in[2];
    const float* w1_1 = (const float*)d_in[3];
    const float* b1_1 = (const float*)d_in[4];
    const float* w2_1 = (const float*)d_in[5];
    const float* b2_1 = (const float*)d_in[6];
    const float* ws1  = (const float*)d_in[7];   // [4][10][10]
    const float* bs1  = (const float*)d_in[8];   // [4][10]
    const float* ws2  = (const float*)d_in[9];   // [4][10][10]
    const float* bs2  = (const float*)d_in[10];  // [4][10]
    const float* lw   = (const float*)d_in[11];  // [5][10]
    float* out = (float*)d_out;

    const int* src = ei;
    const int* dst = ei + N_EDGES;

    // ---- workspace layout (u32 units) ----
    int* bstart      = (int*)d_ws;                      // [NB+1]          @0
    int* rowstart    = (int*)d_ws + 784;                // [N+1]           @784
    unsigned* histg  = (unsigned*)d_ws + 200800;        // [NBLK*NB]       @200800
    unsigned* packed = histg + (size_t)NBLK * NB;       // [E]  (dead after node_sort; reused as tA1)
    unsigned* tA1    = packed;                          // [N*5] overlay
    unsigned* ecol   = packed + N_EDGES;                // [E]
    unsigned* tA0    = ecol + N_EDGES;                  // [N*5]
    float* pooled = (float*)(tA0 + (size_t)N_NODES * RSTRIDE); // [5][G][10]
    size_t needed = (size_t)((char*)(pooled + 5 * NGRAPH * DIM) - (char*)d_ws);
    if (needed > ws_size) return;  // loud failure (output stays zero)

    const int TB = 256;
    int nblocks = (N_NODES + TB - 1) / TB;
    int gblocks = (NGRAPH + TB - 1) / TB;

    hipMemsetAsync(pooled, 0, (size_t)5 * NGRAPH * DIM * sizeof(float), stream);

    // ---- build per-node CSR: hist -> scan -> single-pass scatter -> node sort ----
    khist<<<NBLK, STB, 0, stream>>>(dst, histg);
    kscan<<<1, 1024, 0, stream>>>(histg, bstart);
    kscatter<<<NBLK, STB, 0, stream>>>(src, dst, histg, packed);
    node_sort<<<NB, BNODES, 0, stream>>>(packed, bstart, ecol, rowstart);

    // ---- layer 1 (pre-applied w1) ----
    xform_kernel<<<nblocks, TB, 0, stream>>>(x, w1_1, tA0);
    gin_gather2<true><<<N_NODES / 16, TB, 0, stream>>>(tA0, rowstart, ecol,
        nullptr, b1_1, w2_1, b2_1, batch, tA1, pooled);

    // ---- layers 2..5 (ping-pong tA1 <-> tA0) ----
    unsigned *tin = tA1, *tout2 = tA0;
    for (int l = 0; l < 4; l++) {
        gin_gather2<false><<<N_NODES / 16, TB, 0, stream>>>(tin, rowstart, ecol,
            ws1 + (size_t)l * DIM * DIM, bs1 + (size_t)l * DIM,
            ws2 + (size_t)l * DIM * DIM, bs2 + (size_t)l * DIM,
            batch, tout2, pooled + (size_t)(l + 1) * NGRAPH * DIM);
        unsigned* t = tin; tin = tout2; tout2 = t;
    }

    // ---- readout ----
    final_kernel<<<gblocks, TB, 0, stream>>>(pooled, batch, lw, out);
}

// Round 10
// 620.242 us; speedup vs baseline: 3.1315x; 1.1318x over previous
//
#include <hip/hip_runtime.h>
#include <math.h>

#define N_NODES 200000
#define N_EDGES 5000000
#define NFEAT 16
#define DIM 10
#define NGRAPH 1000
#define BSH 8            // 256 nodes per dst bucket
#define BNODES 256
#define NB ((N_NODES + BNODES - 1) / BNODES)   // 782
#define NBLK 512         // hist/scatter blocks
#define STB 512          // hist/scatter block size
#define RSTRIDE 5        // row stride in u32 (20B) -> 4.0MB table, per-XCD-L2-fit

// pack two f32 -> two bf16 (RNE) in one u32
__device__ __forceinline__ unsigned pkbf(float a, float b) {
    unsigned ua = __float_as_uint(a), ub = __float_as_uint(b);
    ua = (ua + 0x7fffu + ((ua >> 16) & 1u)) >> 16;
    ub = (ub + 0x7fffu + ((ub >> 16) & 1u)) >> 16;
    return ua | (ub << 16);
}
__device__ __forceinline__ float uplo(unsigned u) { return __uint_as_float(u << 16); }
__device__ __forceinline__ float uphi(unsigned u) { return __uint_as_float(u & 0xffff0000u); }

// ---------- pass 1: per-block bucket histogram -> histg[block][NB] ----------
__global__ void __launch_bounds__(STB)
khist(const int* __restrict__ dst, unsigned* __restrict__ histg) {
    __shared__ int h[NB];
    for (int t = threadIdx.x; t < NB; t += STB) h[t] = 0;
    __syncthreads();
    int per = (N_EDGES + NBLK - 1) / NBLK;
    int e0 = blockIdx.x * per;
    int e1 = e0 + per; if (e1 > N_EDGES) e1 = N_EDGES;
    int e = e0 + threadIdx.x;
    for (; e + 7 * STB < e1; e += 8 * STB) {
        int d0 = __builtin_nontemporal_load(&dst[e]);
        int d1 = __builtin_nontemporal_load(&dst[e + STB]);
        int d2 = __builtin_nontemporal_load(&dst[e + 2 * STB]);
        int d3 = __builtin_nontemporal_load(&dst[e + 3 * STB]);
        int d4 = __builtin_nontemporal_load(&dst[e + 4 * STB]);
        int d5 = __builtin_nontemporal_load(&dst[e + 5 * STB]);
        int d6 = __builtin_nontemporal_load(&dst[e + 6 * STB]);
        int d7 = __builtin_nontemporal_load(&dst[e + 7 * STB]);
        atomicAdd(&h[d0 >> BSH], 1); atomicAdd(&h[d1 >> BSH], 1);
        atomicAdd(&h[d2 >> BSH], 1); atomicAdd(&h[d3 >> BSH], 1);
        atomicAdd(&h[d4 >> BSH], 1); atomicAdd(&h[d5 >> BSH], 1);
        atomicAdd(&h[d6 >> BSH], 1); atomicAdd(&h[d7 >> BSH], 1);
    }
    for (; e < e1; e += STB)
        atomicAdd(&h[__builtin_nontemporal_load(&dst[e]) >> BSH], 1);
    __syncthreads();
    for (int t = threadIdx.x; t < NB; t += STB)
        histg[(size_t)blockIdx.x * NB + t] = h[t];
}

// ---------- pass 2: hierarchical scan ----------
__global__ void __launch_bounds__(1024)
kscan(unsigned* __restrict__ histg, int* __restrict__ bstart) {
    __shared__ int tot[NB];
    __shared__ int bst[NB];
    int t = threadIdx.x;
    if (t < NB) {
        int s = 0;
        for (int blk = 0; blk < NBLK; ++blk) s += histg[(size_t)blk * NB + t];
        tot[t] = s;
    }
    __syncthreads();
    if (t == 0) {
        int acc = 0;
        for (int i = 0; i < NB; ++i) { int c = tot[i]; bst[i] = acc; acc += c; }
    }
    __syncthreads();
    if (t < NB) {
        int run = bst[t];
        for (int blk = 0; blk < NBLK; ++blk) {
            unsigned c = histg[(size_t)blk * NB + t];
            histg[(size_t)blk * NB + t] = run;
            run += c;
        }
        bstart[t] = bst[t];
    }
    if (t == 0) bstart[NB] = N_EDGES;
}

// ---------- pass 3: single-pass scatter from precomputed bases ----------
__global__ void __launch_bounds__(STB)
kscatter(const int* __restrict__ src, const int* __restrict__ dst,
         const unsigned* __restrict__ histg, unsigned* __restrict__ packed) {
    __shared__ int wp[NB];
    for (int t = threadIdx.x; t < NB; t += STB)
        wp[t] = histg[(size_t)blockIdx.x * NB + t];
    __syncthreads();
    int per = (N_EDGES + NBLK - 1) / NBLK;
    int e0 = blockIdx.x * per;
    int e1 = e0 + per; if (e1 > N_EDGES) e1 = N_EDGES;
    int e = e0 + threadIdx.x;
    for (; e + 7 * STB < e1; e += 8 * STB) {
        int d[8], s[8];
#pragma unroll
        for (int k = 0; k < 8; ++k) {
            d[k] = __builtin_nontemporal_load(&dst[e + k * STB]);
            s[k] = __builtin_nontemporal_load(&src[e + k * STB]);
        }
#pragma unroll
        for (int k = 0; k < 8; ++k) {
            int r = atomicAdd(&wp[d[k] >> BSH], 1);
            packed[r] = ((unsigned)s[k] << BSH) | (unsigned)(d[k] & (BNODES - 1));
        }
    }
    for (; e < e1; e += STB) {
        int dv = __builtin_nontemporal_load(&dst[e]);
        int sv = __builtin_nontemporal_load(&src[e]);
        int r = atomicAdd(&wp[dv >> BSH], 1);
        packed[r] = ((unsigned)sv << BSH) | (unsigned)(dv & (BNODES - 1));
    }
}

// ---------- pass 4: per-bucket counting sort by dstLocal -> per-node CSR ----------
__global__ void __launch_bounds__(BNODES)
node_sort(const unsigned* __restrict__ pin, const int* __restrict__ bstart,
          unsigned* __restrict__ ecol, int* __restrict__ rowstart) {
    __shared__ int cnt[BNODES];
    __shared__ int cur[BNODES];
    int b = blockIdx.x;
    int e0 = bstart[b], e1 = bstart[b + 1];
    int tid = threadIdx.x;
    cnt[tid] = 0;
    __syncthreads();
    int e = e0 + tid;
    for (; e + 7 * BNODES < e1; e += 8 * BNODES) {
        unsigned p[8];
#pragma unroll
        for (int k = 0; k < 8; ++k) p[k] = __builtin_nontemporal_load(&pin[e + k * BNODES]);
#pragma unroll
        for (int k = 0; k < 8; ++k) atomicAdd(&cnt[p[k] & (BNODES - 1)], 1);
    }
    for (; e < e1; e += BNODES)
        atomicAdd(&cnt[__builtin_nontemporal_load(&pin[e]) & (BNODES - 1)], 1);
    __syncthreads();
    if (tid == 0) {
        int acc = 0;
        for (int t = 0; t < BNODES; ++t) { int c = cnt[t]; cur[t] = acc; acc += c; }
    }
    __syncthreads();
    int n0 = b << BSH;
    if (n0 + tid < N_NODES) rowstart[n0 + tid] = e0 + cur[tid];
    if (b == 0 && tid == 0) rowstart[N_NODES] = N_EDGES;
    e = e0 + tid;
    for (; e + 3 * BNODES < e1; e += 4 * BNODES) {
        unsigned p[4];
#pragma unroll
        for (int k = 0; k < 4; ++k) p[k] = __builtin_nontemporal_load(&pin[e + k * BNODES]);
#pragma unroll
        for (int k = 0; k < 4; ++k) {
            int slot = atomicAdd(&cur[p[k] & (BNODES - 1)], 1);
            ecol[e0 + slot] = p[k] >> BSH;
        }
    }
    for (; e < e1; e += BNODES) {
        unsigned p = __builtin_nontemporal_load(&pin[e]);
        int slot = atomicAdd(&cur[p & (BNODES - 1)], 1);
        ecol[e0 + slot] = p >> BSH;
    }
}

// ---------- y = x @ w1_1 -> bf16 rows, 20B stride ----------
__global__ void xform_kernel(const float* __restrict__ x,
                             const float* __restrict__ w1,   // [16][10]
                             unsigned* __restrict__ tout) {  // [N][5] u32
    int i = blockIdx.x * blockDim.x + threadIdx.x;
    if (i >= N_NODES) return;
    float xi[NFEAT];
    const float4* xr = reinterpret_cast<const float4*>(x + (size_t)i * NFEAT);
#pragma unroll
    for (int q = 0; q < 4; q++) {
        float4 v = xr[q];
        xi[q*4+0] = v.x; xi[q*4+1] = v.y; xi[q*4+2] = v.z; xi[q*4+3] = v.w;
    }
    float o[DIM];
#pragma unroll
    for (int j = 0; j < DIM; j++) {
        float s = 0.f;
#pragma unroll
        for (int f = 0; f < NFEAT; f++) s += xi[f] * w1[f * DIM + j];
        o[j] = s;
    }
#pragma unroll
    for (int k = 0; k < 5; k++)
        __builtin_nontemporal_store(pkbf(o[2*k], o[2*k+1]),
                                    &tout[(size_t)RSTRIDE * i + k]);
}

// ---------- variant A: dim-owner gather (R9 kernel) ----------
template <bool FIRST>
__global__ void __launch_bounds__(256, 8)
gin_gather2(const unsigned* __restrict__ tin,
            const int* __restrict__ rowstart,
            const unsigned* __restrict__ ecol,
            const float* __restrict__ w1, const float* __restrict__ b1,
            const float* __restrict__ w2, const float* __restrict__ b2,
            const int* __restrict__ batch,
            unsigned* __restrict__ tout,
            float* __restrict__ pooled) {
    __shared__ float hp[16][DIM];
    __shared__ int gid[16];
    int tid = threadIdx.x;
    int grp = tid >> 4;
    int j = tid & 15;
    int lane = tid & 63;
    int base = lane & 48;
    int i = blockIdx.x * 16 + grp;

    int r0 = rowstart[i];
    int r1 = rowstart[i + 1];

    int word = j >> 1;
    bool hi = (j & 1);
    const unsigned* tw = tin + word;
    unsigned wown = (j < DIM) ? tw[(size_t)i * RSTRIDE] : 0u;
    float acc = (j < DIM) ? (hi ? uphi(wown) : uplo(wown)) : 0.f;

    unsigned sv = (r0 + j < r1) ? __builtin_nontemporal_load(&ecol[r0 + j]) : 0u;

    for (int e0 = r0; e0 < r1; e0 += 16) {
        unsigned svn = (e0 + 16 + j < r1) ? __builtin_nontemporal_load(&ecol[e0 + 16 + j]) : 0u;
        int cnt = r1 - e0;
        float vals[16];
        bool act = (j < DIM);
#pragma unroll
        for (int k = 0; k < 16; ++k) {
            unsigned s = __shfl(sv, base + k, 64);
            float v = 0.f;
            if (k < cnt && act) {
                unsigned w = tw[(size_t)s * RSTRIDE];
                v = hi ? uphi(w) : uplo(w);
            }
            vals[k] = v;
        }
#pragma unroll
        for (int k = 0; k < 16; ++k) acc += vals[k];
        sv = svn;
    }

    float t1v;
    if (FIRST) {
        t1v = (j < DIM) ? (acc + b1[j]) : 0.f;
    } else {
        float s1 = (j < DIM) ? b1[j] : 0.f;
#pragma unroll
        for (int f = 0; f < DIM; ++f) {
            float zf = __shfl(acc, base + f, 64);
            if (j < DIM) s1 += zf * w1[f * DIM + j];
        }
        t1v = s1;
    }
    t1v = t1v > 0.f ? t1v : 0.f;

    float s2 = (j < DIM) ? b2[j] : 0.f;
#pragma unroll
    for (int f = 0; f < DIM; ++f) {
        float tf = __shfl(t1v, base + f, 64);
        if (j < DIM) s2 += tf * w2[f * DIM + j];
    }
    float hv = s2 > 0.f ? s2 : 0.f;

    float hnext = __shfl(hv, base + ((j + 1) & 15), 64);
    if (j < DIM && !hi)
        __builtin_nontemporal_store(pkbf(hv, hnext), &tout[(size_t)i * RSTRIDE + word]);

    if (j < DIM) hp[grp][j] = hv;
    if (j == 0) gid[grp] = batch[i];
    __syncthreads();

    if (tid < DIM) {
        int cg = gid[0];
        float s = hp[0][tid];
        for (int n = 1; n < 16; ++n) {
            int g = gid[n];
            float v = hp[n][tid];
            if (g == cg) s += v;
            else { atomicAdd(&pooled[cg * DIM + tid], s); cg = g; s = v; }
        }
        atomicAdd(&pooled[cg * DIM + tid], s);
    }
}

// ---------- variant B: edge-owner gather (A/B experiment) ----------
// Each lane owns one edge: loads the full 20B row (5 dwords, consecutive ->
// L1 absorbs intra-row redundancy), accumulates 10 f32 partials in registers.
// No inner-loop shuffles; all 64 lanes active. Tail: 4-step shfl_xor butterfly.
__global__ void __launch_bounds__(256, 8)
gin_gatherE(const unsigned* __restrict__ tin,
            const int* __restrict__ rowstart,
            const unsigned* __restrict__ ecol,
            const float* __restrict__ w1, const float* __restrict__ b1,
            const float* __restrict__ w2, const float* __restrict__ b2,
            const int* __restrict__ batch,
            unsigned* __restrict__ tout,
            float* __restrict__ pooled) {
    __shared__ float hp[16][DIM];
    __shared__ int gid[16];
    int tid = threadIdx.x;
    int grp = tid >> 4;
    int j = tid & 15;
    int lane = tid & 63;
    int base = lane & 48;
    int i = blockIdx.x * 16 + grp;

    int r0 = rowstart[i];
    int r1 = rowstart[i + 1];

    float a[DIM];
#pragma unroll
    for (int d = 0; d < DIM; ++d) a[d] = 0.f;

    int idx = r0 + j;
    // unroll-2: 10 row-loads + 2 ecol loads in flight per lane
    for (; idx + 16 < r1; idx += 32) {
        unsigned sA = __builtin_nontemporal_load(&ecol[idx]);
        unsigned sB = __builtin_nontemporal_load(&ecol[idx + 16]);
        const unsigned* rA = tin + (size_t)sA * RSTRIDE;
        const unsigned* rB = tin + (size_t)sB * RSTRIDE;
        unsigned wA[5], wB[5];
#pragma unroll
        for (int k = 0; k < 5; ++k) wA[k] = rA[k];
#pragma unroll
        for (int k = 0; k < 5; ++k) wB[k] = rB[k];
#pragma unroll
        for (int k = 0; k < 5; ++k) {
            a[2*k]   += uplo(wA[k]) + uplo(wB[k]);
            a[2*k+1] += uphi(wA[k]) + uphi(wB[k]);
        }
    }
    if (idx < r1) {
        unsigned sA = __builtin_nontemporal_load(&ecol[idx]);
        const unsigned* rA = tin + (size_t)sA * RSTRIDE;
        unsigned wA[5];
#pragma unroll
        for (int k = 0; k < 5; ++k) wA[k] = rA[k];
#pragma unroll
        for (int k = 0; k < 5; ++k) {
            a[2*k]   += uplo(wA[k]);
            a[2*k+1] += uphi(wA[k]);
        }
    }

    // butterfly reduce across the 16-lane group (xor masks 1,2,4,8 stay in-group)
#pragma unroll
    for (int m = 1; m <= 8; m <<= 1) {
#pragma unroll
        for (int d = 0; d < DIM; ++d) a[d] += __shfl_xor(a[d], m, 64);
    }

    // own row: every lane loads (group-uniform -> broadcast), full z per lane
    const unsigned* ri = tin + (size_t)i * RSTRIDE;
    float z[DIM];
#pragma unroll
    for (int k = 0; k < 5; ++k) {
        unsigned w = ri[k];
        z[2*k]   = uplo(w) + a[2*k];
        z[2*k+1] = uphi(w) + a[2*k+1];
    }

    // MLP: lane j<10 computes column j of both matmuls (first needs no shfl:
    // every lane holds full z)
    float t1v = 0.f;
    if (j < DIM) {
        float s1 = b1[j];
#pragma unroll
        for (int f = 0; f < DIM; ++f) s1 += z[f] * w1[f * DIM + j];
        t1v = s1 > 0.f ? s1 : 0.f;
    }
    float s2 = (j < DIM) ? b2[j] : 0.f;
#pragma unroll
    for (int f = 0; f < DIM; ++f) {
        float tf = __shfl(t1v, base + f, 64);
        if (j < DIM) s2 += tf * w2[f * DIM + j];
    }
    float hv = s2 > 0.f ? s2 : 0.f;

    float hnext = __shfl(hv, base + ((j + 1) & 15), 64);
    if (j < DIM && !(j & 1))
        __builtin_nontemporal_store(pkbf(hv, hnext), &tout[(size_t)i * RSTRIDE + (j >> 1)]);

    if (j < DIM) hp[grp][j] = hv;
    if (j == 0) gid[grp] = batch[i];
    __syncthreads();

    if (tid < DIM) {
        int cg = gid[0];
        float s = hp[0][tid];
        for (int n = 1; n < 16; ++n) {
            int g = gid[n];
            float v = hp[n][tid];
            if (g == cg) s += v;
            else { atomicAdd(&pooled[cg * DIM + tid], s); cg = g; s = v; }
        }
        atomicAdd(&pooled[cg * DIM + tid], s);
    }
}

// ---------- readout ----------
__global__ void final_kernel(const float* __restrict__ pooled,  // [5][G][10]
                             const int* __restrict__ batch,
                             const float* __restrict__ lw,      // [5][10]
                             float* __restrict__ out) {
    int g = blockIdx.x * blockDim.x + threadIdx.x;
    if (g >= NGRAPH) return;
    int lo = 0, hi = N_NODES;
    while (lo < hi) { int m = (lo + hi) >> 1; if (batch[m] < g) lo = m + 1; else hi = m; }
    int a = lo;
    hi = N_NODES;
    while (lo < hi) { int m = (lo + hi) >> 1; if (batch[m] < g + 1) lo = m + 1; else hi = m; }
    float c = (float)(lo - a);
    float inv = 1.0f / (c > 1.f ? c : 1.f);
    float s = 0.f;
#pragma unroll
    for (int l = 0; l < 5; l++) {
        float d = 0.f;
#pragma unroll
        for (int j = 0; j < DIM; j++)
            d += pooled[(size_t)l * NGRAPH * DIM + (size_t)g * DIM + j] * lw[l * DIM + j];
        s += d * inv;
    }
    out[g] = 1.0f / (1.0f + expf(-s));
}

extern "C" void kernel_launch(void* const* d_in, const int* in_sizes, int n_in,
                              void* d_out, int out_size, void* d_ws, size_t ws_size,
                              hipStream_t stream) {
    const float* x    = (const float*)d_in[0];
    const int*   ei   = (const int*)d_in[1];
    const int*   batch= (const int*)d_in[2];
    const float* w1_1 = (const float*)d_in[3];
    const float* b1_1 = (const float*)d_in[4];
    const float* w2_1 = (const float*)d_in[5];
    const float* b2_1 = (const float*)d_in[6];
    const float* ws1  = (const float*)d_in[7];   // [4][10][10]
    const float* bs1  = (const float*)d_in[8];   // [4][10]
    const float* ws2  = (const float*)d_in[9];   // [4][10][10]
    const float* bs2  = (const float*)d_in[10];  // [4][10]
    const float* lw   = (const float*)d_in[11];  // [5][10]
    float* out = (float*)d_out;

    const int* src = ei;
    const int* dst = ei + N_EDGES;

    // ---- workspace layout (u32 units) ----
    int* bstart      = (int*)d_ws;                      // [NB+1]          @0
    int* rowstart    = (int*)d_ws + 784;                // [N+1]           @784
    unsigned* histg  = (unsigned*)d_ws + 200800;        // [NBLK*NB]       @200800
    unsigned* packed = histg + (size_t)NBLK * NB;       // [E] (dead after node_sort; reused as tA1)
    unsigned* tA1    = packed;                          // [N*5] overlay
    unsigned* ecol   = packed + N_EDGES;                // [E]
    unsigned* tA0    = ecol + N_EDGES;                  // [N*5]
    float* pooled = (float*)(tA0 + (size_t)N_NODES * RSTRIDE); // [5][G][10]
    size_t needed = (size_t)((char*)(pooled + 5 * NGRAPH * DIM) - (char*)d_ws);
    if (needed > ws_size) return;  // loud failure (output stays zero)

    const int TB = 256;
    int nblocks = (N_NODES + TB - 1) / TB;
    int gblocks = (NGRAPH + TB - 1) / TB;

    hipMemsetAsync(pooled, 0, (size_t)5 * NGRAPH * DIM * sizeof(float), stream);

    // ---- build per-node CSR ----
    khist<<<NBLK, STB, 0, stream>>>(dst, histg);
    kscan<<<1, 1024, 0, stream>>>(histg, bstart);
    kscatter<<<NBLK, STB, 0, stream>>>(src, dst, histg, packed);
    node_sort<<<NB, BNODES, 0, stream>>>(packed, bstart, ecol, rowstart);

    // ---- layer 1 (pre-applied w1), variant A ----
    xform_kernel<<<nblocks, TB, 0, stream>>>(x, w1_1, tA0);
    gin_gather2<true><<<N_NODES / 16, TB, 0, stream>>>(tA0, rowstart, ecol,
        nullptr, b1_1, w2_1, b2_1, batch, tA1, pooled);

    // ---- layers 2..5: A/B — layers 2,4 variant A (dim-owner), 3,5 variant B (edge-owner) ----
    unsigned *tin = tA1, *tout2 = tA0;
    for (int l = 0; l < 4; l++) {
        const float* W1 = ws1 + (size_t)l * DIM * DIM;
        const float* B1 = bs1 + (size_t)l * DIM;
        const float* W2 = ws2 + (size_t)l * DIM * DIM;
        const float* B2 = bs2 + (size_t)l * DIM;
        float* PL = pooled + (size_t)(l + 1) * NGRAPH * DIM;
        if ((l & 1) == 0) {   // layers 2, 4 -> variant A
            gin_gather2<false><<<N_NODES / 16, TB, 0, stream>>>(
                tin, rowstart, ecol, W1, B1, W2, B2, batch, tout2, PL);
        } else {              // layers 3, 5 -> variant B
            gin_gatherE<<<N_NODES / 16, TB, 0, stream>>>(
                tin, rowstart, ecol, W1, B1, W2, B2, batch, tout2, PL);
        }
        unsigned* t = tin; tin = tout2; tout2 = t;
    }

    // ---- readout ----
    final_kernel<<<gblocks, TB, 0, stream>>>(pooled, batch, lw, out);
}

// Round 11
// 499.339 us; speedup vs baseline: 3.8897x; 1.2421x over previous
//
#include <hip/hip_runtime.h>
#include <math.h>

#define N_NODES 200000
#define N_EDGES 5000000
#define NFEAT 16
#define DIM 10
#define NGRAPH 1000
#define BSH 8            // 256 nodes per dst bucket
#define BNODES 256
#define NB ((N_NODES + BNODES - 1) / BNODES)   // 782
#define NBLK 512         // hist/scatter blocks
#define STB 512          // hist/scatter block size
#define RSTRIDE 5        // row stride in u32 (20B) -> 4.0MB table, per-XCD-L2-fit

// pack two f32 -> two bf16 (RNE) in one u32
__device__ __forceinline__ unsigned pkbf(float a, float b) {
    unsigned ua = __float_as_uint(a), ub = __float_as_uint(b);
    ua = (ua + 0x7fffu + ((ua >> 16) & 1u)) >> 16;
    ub = (ub + 0x7fffu + ((ub >> 16) & 1u)) >> 16;
    return ua | (ub << 16);
}
__device__ __forceinline__ float uplo(unsigned u) { return __uint_as_float(u << 16); }
__device__ __forceinline__ float uphi(unsigned u) { return __uint_as_float(u & 0xffff0000u); }

// ---------- pass 1: per-block bucket histogram -> histg[block][NB] ----------
__global__ void __launch_bounds__(STB)
khist(const int* __restrict__ dst, unsigned* __restrict__ histg) {
    __shared__ int h[NB];
    for (int t = threadIdx.x; t < NB; t += STB) h[t] = 0;
    __syncthreads();
    int per = (N_EDGES + NBLK - 1) / NBLK;
    int e0 = blockIdx.x * per;
    int e1 = e0 + per; if (e1 > N_EDGES) e1 = N_EDGES;
    int e = e0 + threadIdx.x;
    for (; e + 7 * STB < e1; e += 8 * STB) {
        int d0 = __builtin_nontemporal_load(&dst[e]);
        int d1 = __builtin_nontemporal_load(&dst[e + STB]);
        int d2 = __builtin_nontemporal_load(&dst[e + 2 * STB]);
        int d3 = __builtin_nontemporal_load(&dst[e + 3 * STB]);
        int d4 = __builtin_nontemporal_load(&dst[e + 4 * STB]);
        int d5 = __builtin_nontemporal_load(&dst[e + 5 * STB]);
        int d6 = __builtin_nontemporal_load(&dst[e + 6 * STB]);
        int d7 = __builtin_nontemporal_load(&dst[e + 7 * STB]);
        atomicAdd(&h[d0 >> BSH], 1); atomicAdd(&h[d1 >> BSH], 1);
        atomicAdd(&h[d2 >> BSH], 1); atomicAdd(&h[d3 >> BSH], 1);
        atomicAdd(&h[d4 >> BSH], 1); atomicAdd(&h[d5 >> BSH], 1);
        atomicAdd(&h[d6 >> BSH], 1); atomicAdd(&h[d7 >> BSH], 1);
    }
    for (; e < e1; e += STB)
        atomicAdd(&h[__builtin_nontemporal_load(&dst[e]) >> BSH], 1);
    __syncthreads();
    for (int t = threadIdx.x; t < NB; t += STB)
        histg[(size_t)blockIdx.x * NB + t] = h[t];
}

// ---------- pass 2: hierarchical scan ----------
__global__ void __launch_bounds__(1024)
kscan(unsigned* __restrict__ histg, int* __restrict__ bstart) {
    __shared__ int tot[NB];
    __shared__ int bst[NB];
    int t = threadIdx.x;
    if (t < NB) {
        int s = 0;
        for (int blk = 0; blk < NBLK; ++blk) s += histg[(size_t)blk * NB + t];
        tot[t] = s;
    }
    __syncthreads();
    if (t == 0) {
        int acc = 0;
        for (int i = 0; i < NB; ++i) { int c = tot[i]; bst[i] = acc; acc += c; }
    }
    __syncthreads();
    if (t < NB) {
        int run = bst[t];
        for (int blk = 0; blk < NBLK; ++blk) {
            unsigned c = histg[(size_t)blk * NB + t];
            histg[(size_t)blk * NB + t] = run;
            run += c;
        }
        bstart[t] = bst[t];
    }
    if (t == 0) bstart[NB] = N_EDGES;
}

// ---------- pass 3: single-pass scatter from precomputed bases ----------
__global__ void __launch_bounds__(STB)
kscatter(const int* __restrict__ src, const int* __restrict__ dst,
         const unsigned* __restrict__ histg, unsigned* __restrict__ packed) {
    __shared__ int wp[NB];
    for (int t = threadIdx.x; t < NB; t += STB)
        wp[t] = histg[(size_t)blockIdx.x * NB + t];
    __syncthreads();
    int per = (N_EDGES + NBLK - 1) / NBLK;
    int e0 = blockIdx.x * per;
    int e1 = e0 + per; if (e1 > N_EDGES) e1 = N_EDGES;
    int e = e0 + threadIdx.x;
    for (; e + 7 * STB < e1; e += 8 * STB) {
        int d[8], s[8];
#pragma unroll
        for (int k = 0; k < 8; ++k) {
            d[k] = __builtin_nontemporal_load(&dst[e + k * STB]);
            s[k] = __builtin_nontemporal_load(&src[e + k * STB]);
        }
#pragma unroll
        for (int k = 0; k < 8; ++k) {
            int r = atomicAdd(&wp[d[k] >> BSH], 1);
            packed[r] = ((unsigned)s[k] << BSH) | (unsigned)(d[k] & (BNODES - 1));
        }
    }
    for (; e < e1; e += STB) {
        int dv = __builtin_nontemporal_load(&dst[e]);
        int sv = __builtin_nontemporal_load(&src[e]);
        int r = atomicAdd(&wp[dv >> BSH], 1);
        packed[r] = ((unsigned)sv << BSH) | (unsigned)(dv & (BNODES - 1));
    }
}

// ---------- pass 4: per-bucket counting sort by dstLocal -> per-node CSR ----------
__global__ void __launch_bounds__(BNODES)
node_sort(const unsigned* __restrict__ pin, const int* __restrict__ bstart,
          unsigned* __restrict__ ecol, int* __restrict__ rowstart) {
    __shared__ int cnt[BNODES];
    __shared__ int cur[BNODES];
    int b = blockIdx.x;
    int e0 = bstart[b], e1 = bstart[b + 1];
    int tid = threadIdx.x;
    cnt[tid] = 0;
    __syncthreads();
    int e = e0 + tid;
    for (; e + 7 * BNODES < e1; e += 8 * BNODES) {
        unsigned p[8];
#pragma unroll
        for (int k = 0; k < 8; ++k) p[k] = __builtin_nontemporal_load(&pin[e + k * BNODES]);
#pragma unroll
        for (int k = 0; k < 8; ++k) atomicAdd(&cnt[p[k] & (BNODES - 1)], 1);
    }
    for (; e < e1; e += BNODES)
        atomicAdd(&cnt[__builtin_nontemporal_load(&pin[e]) & (BNODES - 1)], 1);
    __syncthreads();
    if (tid == 0) {
        int acc = 0;
        for (int t = 0; t < BNODES; ++t) { int c = cnt[t]; cur[t] = acc; acc += c; }
    }
    __syncthreads();
    int n0 = b << BSH;
    if (n0 + tid < N_NODES) rowstart[n0 + tid] = e0 + cur[tid];
    if (b == 0 && tid == 0) rowstart[N_NODES] = N_EDGES;
    e = e0 + tid;
    for (; e + 3 * BNODES < e1; e += 4 * BNODES) {
        unsigned p[4];
#pragma unroll
        for (int k = 0; k < 4; ++k) p[k] = __builtin_nontemporal_load(&pin[e + k * BNODES]);
#pragma unroll
        for (int k = 0; k < 4; ++k) {
            int slot = atomicAdd(&cur[p[k] & (BNODES - 1)], 1);
            ecol[e0 + slot] = p[k] >> BSH;
        }
    }
    for (; e < e1; e += BNODES) {
        unsigned p = __builtin_nontemporal_load(&pin[e]);
        int slot = atomicAdd(&cur[p & (BNODES - 1)], 1);
        ecol[e0 + slot] = p >> BSH;
    }
}

// ---------- y = x @ w1_1 -> bf16 rows, 20B stride ----------
__global__ void xform_kernel(const float* __restrict__ x,
                             const float* __restrict__ w1,   // [16][10]
                             unsigned* __restrict__ tout) {  // [N][5] u32
    int i = blockIdx.x * blockDim.x + threadIdx.x;
    if (i >= N_NODES) return;
    float xi[NFEAT];
    const float4* xr = reinterpret_cast<const float4*>(x + (size_t)i * NFEAT);
#pragma unroll
    for (int q = 0; q < 4; q++) {
        float4 v = xr[q];
        xi[q*4+0] = v.x; xi[q*4+1] = v.y; xi[q*4+2] = v.z; xi[q*4+3] = v.w;
    }
    float o[DIM];
#pragma unroll
    for (int j = 0; j < DIM; j++) {
        float s = 0.f;
#pragma unroll
        for (int f = 0; f < NFEAT; f++) s += xi[f] * w1[f * DIM + j];
        o[j] = s;
    }
#pragma unroll
    for (int k = 0; k < 5; k++)
        __builtin_nontemporal_store(pkbf(o[2*k], o[2*k+1]),
                                    &tout[(size_t)RSTRIDE * i + k]);
}

// ---------- edge-owner gather + MLP + pool (winner of R10 A/B) ----------
// Each lane owns one edge: loads the full 20B row (5 consecutive dwords; L1
// absorbs intra-row redundancy), accumulates 10 f32 partials in registers.
// Unroll-4: 4 ecol + 20 row-loads in flight per lane. 16-lane butterfly tail.
template <bool FIRST>
__global__ void __launch_bounds__(256, 8)
gin_gatherE(const unsigned* __restrict__ tin,
            const int* __restrict__ rowstart,
            const unsigned* __restrict__ ecol,
            const float* __restrict__ w1, const float* __restrict__ b1,
            const float* __restrict__ w2, const float* __restrict__ b2,
            const int* __restrict__ batch,
            unsigned* __restrict__ tout,
            float* __restrict__ pooled) {
    __shared__ float hp[16][DIM];
    __shared__ int gid[16];
    int tid = threadIdx.x;
    int grp = tid >> 4;
    int j = tid & 15;
    int lane = tid & 63;
    int base = lane & 48;
    int i = blockIdx.x * 16 + grp;

    int r0 = rowstart[i];
    int r1 = rowstart[i + 1];

    float a[DIM];
#pragma unroll
    for (int d = 0; d < DIM; ++d) a[d] = 0.f;

    int idx = r0 + j;
    for (; idx + 48 < r1; idx += 64) {
        unsigned sv[4];
#pragma unroll
        for (int u = 0; u < 4; ++u)
            sv[u] = __builtin_nontemporal_load(&ecol[idx + 16 * u]);
        unsigned w[4][5];
#pragma unroll
        for (int u = 0; u < 4; ++u) {
            const unsigned* r = tin + (size_t)sv[u] * RSTRIDE;
#pragma unroll
            for (int k = 0; k < 5; ++k) w[u][k] = r[k];
        }
#pragma unroll
        for (int u = 0; u < 4; ++u)
#pragma unroll
            for (int k = 0; k < 5; ++k) {
                a[2*k]   += uplo(w[u][k]);
                a[2*k+1] += uphi(w[u][k]);
            }
    }
    for (; idx + 16 < r1; idx += 32) {
        unsigned sA = __builtin_nontemporal_load(&ecol[idx]);
        unsigned sB = __builtin_nontemporal_load(&ecol[idx + 16]);
        const unsigned* rA = tin + (size_t)sA * RSTRIDE;
        const unsigned* rB = tin + (size_t)sB * RSTRIDE;
        unsigned wA[5], wB[5];
#pragma unroll
        for (int k = 0; k < 5; ++k) wA[k] = rA[k];
#pragma unroll
        for (int k = 0; k < 5; ++k) wB[k] = rB[k];
#pragma unroll
        for (int k = 0; k < 5; ++k) {
            a[2*k]   += uplo(wA[k]) + uplo(wB[k]);
            a[2*k+1] += uphi(wA[k]) + uphi(wB[k]);
        }
    }
    if (idx < r1) {
        unsigned sA = __builtin_nontemporal_load(&ecol[idx]);
        const unsigned* rA = tin + (size_t)sA * RSTRIDE;
        unsigned wA[5];
#pragma unroll
        for (int k = 0; k < 5; ++k) wA[k] = rA[k];
#pragma unroll
        for (int k = 0; k < 5; ++k) {
            a[2*k]   += uplo(wA[k]);
            a[2*k+1] += uphi(wA[k]);
        }
    }

    // butterfly reduce across the 16-lane group
#pragma unroll
    for (int m = 1; m <= 8; m <<= 1) {
#pragma unroll
        for (int d = 0; d < DIM; ++d) a[d] += __shfl_xor(a[d], m, 64);
    }

    // own row (group-uniform load -> broadcast); full z per lane
    const unsigned* ri = tin + (size_t)i * RSTRIDE;
    float z[DIM];
#pragma unroll
    for (int k = 0; k < 5; ++k) {
        unsigned w = ri[k];
        z[2*k]   = uplo(w) + a[2*k];
        z[2*k+1] = uphi(w) + a[2*k+1];
    }

    float t1v = 0.f;
    if (FIRST) {
        if (j < DIM) {
            float s1 = z[j] + b1[j];
            t1v = s1 > 0.f ? s1 : 0.f;
        }
    } else {
        if (j < DIM) {
            float s1 = b1[j];
#pragma unroll
            for (int f = 0; f < DIM; ++f) s1 += z[f] * w1[f * DIM + j];
            t1v = s1 > 0.f ? s1 : 0.f;
        }
    }
    float s2 = (j < DIM) ? b2[j] : 0.f;
#pragma unroll
    for (int f = 0; f < DIM; ++f) {
        float tf = __shfl(t1v, base + f, 64);
        if (j < DIM) s2 += tf * w2[f * DIM + j];
    }
    float hv = s2 > 0.f ? s2 : 0.f;

    float hnext = __shfl(hv, base + ((j + 1) & 15), 64);
    if (j < DIM && !(j & 1))
        __builtin_nontemporal_store(pkbf(hv, hnext), &tout[(size_t)i * RSTRIDE + (j >> 1)]);

    if (j < DIM) hp[grp][j] = hv;
    if (j == 0) gid[grp] = batch[i];
    __syncthreads();

    if (tid < DIM) {
        int cg = gid[0];
        float s = hp[0][tid];
        for (int n = 1; n < 16; ++n) {
            int g = gid[n];
            float v = hp[n][tid];
            if (g == cg) s += v;
            else { atomicAdd(&pooled[cg * DIM + tid], s); cg = g; s = v; }
        }
        atomicAdd(&pooled[cg * DIM + tid], s);
    }
}

// ---------- readout ----------
__global__ void final_kernel(const float* __restrict__ pooled,  // [5][G][10]
                             const int* __restrict__ batch,
                             const float* __restrict__ lw,      // [5][10]
                             float* __restrict__ out) {
    int g = blockIdx.x * blockDim.x + threadIdx.x;
    if (g >= NGRAPH) return;
    int lo = 0, hi = N_NODES;
    while (lo < hi) { int m = (lo + hi) >> 1; if (batch[m] < g) lo = m + 1; else hi = m; }
    int a = lo;
    hi = N_NODES;
    while (lo < hi) { int m = (lo + hi) >> 1; if (batch[m] < g + 1) lo = m + 1; else hi = m; }
    float c = (float)(lo - a);
    float inv = 1.0f / (c > 1.f ? c : 1.f);
    float s = 0.f;
#pragma unroll
    for (int l = 0; l < 5; l++) {
        float d = 0.f;
#pragma unroll
        for (int j = 0; j < DIM; j++)
            d += pooled[(size_t)l * NGRAPH * DIM + (size_t)g * DIM + j] * lw[l * DIM + j];
        s += d * inv;
    }
    out[g] = 1.0f / (1.0f + expf(-s));
}

extern "C" void kernel_launch(void* const* d_in, const int* in_sizes, int n_in,
                              void* d_out, int out_size, void* d_ws, size_t ws_size,
                              hipStream_t stream) {
    const float* x    = (const float*)d_in[0];
    const int*   ei   = (const int*)d_in[1];
    const int*   batch= (const int*)d_in[2];
    const float* w1_1 = (const float*)d_in[3];
    const float* b1_1 = (const float*)d_in[4];
    const float* w2_1 = (const float*)d_in[5];
    const float* b2_1 = (const float*)d_in[6];
    const float* ws1  = (const float*)d_in[7];   // [4][10][10]
    const float* bs1  = (const float*)d_in[8];   // [4][10]
    const float* ws2  = (const float*)d_in[9];   // [4][10][10]
    const float* bs2  = (const float*)d_in[10];  // [4][10]
    const float* lw   = (const float*)d_in[11];  // [5][10]
    float* out = (float*)d_out;

    const int* src = ei;
    const int* dst = ei + N_EDGES;

    // ---- workspace layout (u32 units) ----
    int* bstart      = (int*)d_ws;                      // [NB+1]          @0
    int* rowstart    = (int*)d_ws + 784;                // [N+1]           @784
    unsigned* histg  = (unsigned*)d_ws + 200800;        // [NBLK*NB]       @200800
    unsigned* packed = histg + (size_t)NBLK * NB;       // [E] (dead after node_sort; reused as tA1)
    unsigned* tA1    = packed;                          // [N*5] overlay
    unsigned* ecol   = packed + N_EDGES;                // [E]
    unsigned* tA0    = ecol + N_EDGES;                  // [N*5]
    float* pooled = (float*)(tA0 + (size_t)N_NODES * RSTRIDE); // [5][G][10]
    size_t needed = (size_t)((char*)(pooled + 5 * NGRAPH * DIM) - (char*)d_ws);
    if (needed > ws_size) return;  // loud failure (output stays zero)

    const int TB = 256;
    int nblocks = (N_NODES + TB - 1) / TB;
    int gblocks = (NGRAPH + TB - 1) / TB;

    hipMemsetAsync(pooled, 0, (size_t)5 * NGRAPH * DIM * sizeof(float), stream);

    // ---- build per-node CSR ----
    khist<<<NBLK, STB, 0, stream>>>(dst, histg);
    kscan<<<1, 1024, 0, stream>>>(histg, bstart);
    kscatter<<<NBLK, STB, 0, stream>>>(src, dst, histg, packed);
    node_sort<<<NB, BNODES, 0, stream>>>(packed, bstart, ecol, rowstart);

    // ---- layer 1 (pre-applied w1) ----
    xform_kernel<<<nblocks, TB, 0, stream>>>(x, w1_1, tA0);
    gin_gatherE<true><<<N_NODES / 16, TB, 0, stream>>>(tA0, rowstart, ecol,
        nullptr, b1_1, w2_1, b2_1, batch, tA1, pooled);

    // ---- layers 2..5 (all edge-owner) ----
    unsigned *tin = tA1, *tout2 = tA0;
    for (int l = 0; l < 4; l++) {
        gin_gatherE<false><<<N_NODES / 16, TB, 0, stream>>>(tin, rowstart, ecol,
            ws1 + (size_t)l * DIM * DIM, bs1 + (size_t)l * DIM,
            ws2 + (size_t)l * DIM * DIM, bs2 + (size_t)l * DIM,
            batch, tout2, pooled + (size_t)(l + 1) * NGRAPH * DIM);
        unsigned* t = tin; tin = tout2; tout2 = t;
    }

    // ---- readout ----
    final_kernel<<<gblocks, TB, 0, stream>>>(pooled, batch, lw, out);
}